// Round 4
// baseline (4858.450 us; speedup 1.0000x reference)
//
#include <hip/hip_runtime.h>
#include <stdint.h>
#include <stddef.h>

typedef short bf16x8 __attribute__((ext_vector_type(8)));
typedef unsigned short ushort8 __attribute__((ext_vector_type(8)));
typedef unsigned short usv4 __attribute__((ext_vector_type(4)));
typedef float f32x4 __attribute__((ext_vector_type(4)));

__device__ __forceinline__ unsigned short f2bf(float f) {
  union { float f; unsigned int u; } v; v.f = f;
  unsigned int r = v.u + 0x7FFFu + ((v.u >> 16) & 1u);  // RNE
  return (unsigned short)(r >> 16);
}
__device__ __forceinline__ float bf2f(unsigned short u) {
  union { unsigned int u; float f; } v; v.u = ((unsigned int)u) << 16; return v.f;
}

// ---------------- B fragment-order builder ----------------
// For K-step t, col-group g(0..31), lane(0..63), elem e(0..7):
//   idx = ((t*32 + g)*64 + lane)*8 + e   [16384 ushorts per K-step]
//   col = g*16 + (lane&15);  k = t*32 + (lane>>4)*8 + e
// mode 0: cat-K (W0 400x1000, W1 400x500, W2 400x500); mode 1: W0 [N x Kr];
// mode 2: head (W0=Wlin 20x400, W1=Wd1 50x400)
__global__ void build_bfrag(const float* __restrict__ W0, const float* __restrict__ W1,
                            const float* __restrict__ W2, unsigned short* __restrict__ out,
                            int ksteps, int mode, int N, int Kr)
{
  int idx = blockIdx.x * 256 + threadIdx.x;
  int total = ksteps * 16384;
  if (idx >= total) return;
  int t = idx >> 14;
  int rem = idx & 16383;
  int e = rem & 7;
  int chunk = rem >> 3;
  int lane = chunk & 63;
  int g = chunk >> 6;
  int col = g * 16 + (lane & 15);
  int k = t * 32 + ((lane >> 4) << 3) + e;
  float v = 0.f;
  if (mode == 0) {
    if (col < 400 && k < 2000) {
      if (k < 1000)      v = W0[col * 1000 + k];
      else if (k < 1500) v = W1[col * 500 + (k - 1000)];
      else               v = W2[col * 500 + (k - 1500)];
    }
  } else if (mode == 1) {
    if (col < N && k < Kr) v = W0[col * Kr + k];
  } else {
    if (k < 400) {
      if (col < 20)      v = W0[col * 400 + k];
      else if (col < 70) v = W1[(col - 20) * 400 + k];
    }
  }
  out[idx] = f2bf(v);
}

__global__ void build_bias3(const float* a, const float* b, const float* c, float* o) {
  int i = blockIdx.x * 256 + threadIdx.x;
  if (i < 416) o[i] = (i < 400) ? (a[i] + b[i] + c[i]) : 0.f;
}
__global__ void build_bhead(const float* blin, const float* bd1, float* o) {
  int i = threadIdx.x;
  if (i < 512) o[i] = (i < 20) ? blin[i] : ((i < 70) ? bd1[i - 20] : 0.f);
}

// ---------------- MFMA GEMM: 128x512 block, 1024 thr = 16 waves (2M x 8N) ----------------
// Wave tile 64x64 (mi=4, ni=4). A staged in LDS (bf16, dbuf, pad-36). B frags loaded
// directly from fragment-ordered global into registers (dbuf, 2 steps ahead).
// AMODE 0: A f32 (cvt at LDS-write); AMODE 1: A bf16 stride Astride.
// OMODE 0: C bf16 [M][416]; OMODE 1: head split f32 (col<20 -> Cv[M][20], 20..69 -> C2[M][50]).
template<int AMODE, int OMODE>
__global__ __launch_bounds__(1024) void gemm1024(
    const void* __restrict__ Av, const unsigned short* __restrict__ Bf,
    const float* __restrict__ bias, void* __restrict__ Cv, float* __restrict__ C2,
    int M, int Kreal, int Astride, int ksteps, int Nreal)
{
  __shared__ unsigned short As[2][128][36];
  const int tid = threadIdx.x;
  const int lane = tid & 63;
  const int wv = tid >> 6;          // 0..15
  const int wr = wv >> 3;           // 0..1
  const int wc = wv & 7;            // 0..7
  const int rowBase = blockIdx.x * 128;
  const int sRow = tid >> 3;        // 0..127
  const int sC = (tid & 7) << 2;    // 0,4,...,28
  const int aRow = rowBase + sRow;
  const bool aOK = aRow < M;
  const int fr = lane & 15;
  const int fq = lane >> 4;

  const float* Af = (const float*)Av;
  const unsigned short* Ah = (const unsigned short*)Av;
  // per-wave B base offset (ushorts): frag g = wc*4+ni at +ni*512
  const unsigned short* bWave = Bf + ((size_t)(wc * 4) * 64 + lane) * 8;

  f32x4 acc[4][4] = {};
  f32x4 aRegF;
  usv4 aRegH;
  ushort8 bA[4], bB[4];

  auto loadA = [&](int t) {
    const int k0 = t * 32 + sC;
    if (AMODE == 0) {
      if (aOK && (k0 + 4) <= Kreal) aRegF = *(const f32x4*)(Af + (size_t)aRow * Astride + k0);
      else { aRegF[0] = 0.f; aRegF[1] = 0.f; aRegF[2] = 0.f; aRegF[3] = 0.f; }
    } else {
      if (aOK) aRegH = *(const usv4*)(Ah + (size_t)aRow * Astride + k0);
      else { aRegH[0] = 0; aRegH[1] = 0; aRegH[2] = 0; aRegH[3] = 0; }
    }
  };
  auto writeA = [&](int buf) {
    usv4 w;
    if (AMODE == 0) {
      #pragma unroll
      for (int j = 0; j < 4; ++j) w[j] = f2bf(aRegF[j]);
    } else w = aRegH;
    *(usv4*)&As[buf][sRow][sC] = w;
  };
  auto loadB = [&](ushort8* dst, int t) {
    const unsigned short* bp = bWave + (size_t)t * 16384;
    #pragma unroll
    for (int ni = 0; ni < 4; ++ni) dst[ni] = *(const ushort8*)(bp + ni * 512);
  };
  auto compute = [&](int buf, ushort8* bfr) {
    bf16x8 af[4];
    #pragma unroll
    for (int mi = 0; mi < 4; ++mi)
      af[mi] = *(const bf16x8*)&As[buf][(wr << 6) + (mi << 4) + fr][fq << 3];
    #pragma unroll
    for (int ni = 0; ni < 4; ++ni) {
      bf16x8 bv;
      #pragma unroll
      for (int j = 0; j < 8; ++j) bv[j] = (short)bfr[ni][j];
      #pragma unroll
      for (int mi = 0; mi < 4; ++mi)
        acc[mi][ni] = __builtin_amdgcn_mfma_f32_16x16x32_bf16(af[mi], bv, acc[mi][ni], 0, 0, 0);
    }
  };

  // prologue
  loadA(0); loadB(bA, 0);
  writeA(0);
  if (ksteps > 1) { loadA(1); loadB(bB, 1); }
  __syncthreads();

  for (int t = 0; t < ksteps; ++t) {
    if ((t & 1) == 0) {
      compute(0, bA);
      if (t + 1 < ksteps) {
        writeA(1);
        if (t + 2 < ksteps) { loadA(t + 2); loadB(bA, t + 2); }
        __syncthreads();
      }
    } else {
      compute(1, bB);
      if (t + 1 < ksteps) {
        writeA(0);
        if (t + 2 < ksteps) { loadA(t + 2); loadB(bB, t + 2); }
        __syncthreads();
      }
    }
  }

  // epilogue: C/D layout col=lane&15, row=(lane>>4)*4+r [m89]
  #pragma unroll
  for (int mi = 0; mi < 4; ++mi) {
    const int row0 = rowBase + (wr << 6) + (mi << 4) + (fq << 2);
    #pragma unroll
    for (int ni = 0; ni < 4; ++ni) {
      const int col = (wc << 6) + (ni << 4) + fr;
      if (OMODE == 0) {
        if (col < 416) {
          unsigned short* C = (unsigned short*)Cv;
          const float bv = (col < Nreal) ? bias[col] : 0.f;
          #pragma unroll
          for (int r = 0; r < 4; ++r) {
            const int row = row0 + r;
            if (row < M) C[(size_t)row * 416 + col] =
                (col < Nreal) ? f2bf(acc[mi][ni][r] + bv) : (unsigned short)0;
          }
        }
      } else {
        if (col < 70) {
          const float bv = bias[col];
          #pragma unroll
          for (int r = 0; r < 4; ++r) {
            const int row = row0 + r;
            if (row < M) {
              float v = acc[mi][ni][r] + bv;
              if (col < 20) ((float*)Cv)[(size_t)row * 20 + col] = v;
              else          C2[(size_t)row * 50 + (col - 20)] = v;
            }
          }
        }
      }
    }
  }
}

// ---------------- CSR build ----------------
__global__ void count_deg(const int* __restrict__ dst, int* __restrict__ cnt, int E) {
  int e = blockIdx.x * 256 + threadIdx.x;
  if (e < E) atomicAdd(&cnt[dst[e]], 1);
}

__global__ void scan_indptr(const int* __restrict__ cnt, int* __restrict__ indptr, int n) {
  __shared__ int sh[1024];
  __shared__ int carrySh;
  const int t = threadIdx.x;
  if (t == 0) carrySh = 0;
  __syncthreads();
  for (int base = 0; base < n; base += 8192) {
    int v[8]; int tsum = 0;
    #pragma unroll
    for (int i = 0; i < 8; ++i) {
      int idx = base + t * 8 + i;
      v[i] = (idx < n) ? cnt[idx] : 0;
      tsum += v[i];
    }
    sh[t] = tsum; __syncthreads();
    for (int off = 1; off < 1024; off <<= 1) {
      int add = (t >= off) ? sh[t - off] : 0;
      __syncthreads();
      sh[t] += add;
      __syncthreads();
    }
    int excl = carrySh + sh[t] - tsum;
    #pragma unroll
    for (int i = 0; i < 8; ++i) {
      int idx = base + t * 8 + i;
      if (idx < n) indptr[idx] = excl;
      excl += v[i];
    }
    __syncthreads();
    if (t == 1023) carrySh += sh[1023];
    __syncthreads();
  }
  if (t == 0) indptr[n] = carrySh;
}

__global__ void fill_csr(const int* __restrict__ src, const int* __restrict__ dst,
                         const int* __restrict__ eid, const float* __restrict__ wall,
                         const int* __restrict__ indptr, int* __restrict__ fillc,
                         int* __restrict__ esrc, float* __restrict__ ew, int E)
{
  int e = blockIdx.x * 256 + threadIdx.x;
  if (e >= E) return;
  int d = dst[e];
  int pos = atomicAdd(&fillc[d], 1);
  int slot = indptr[d] + pos;
  esrc[slot] = src[e];
  ew[slot] = wall[eid[e]];
}

// ---------------- segment mean-aggregate (bf16 in/out, stride 416) ----------------
__global__ __launch_bounds__(256) void seg_mean_bf(
    const unsigned short* __restrict__ h, const int* __restrict__ indptr,
    const int* __restrict__ esrc, const float* __restrict__ ew,
    unsigned short* __restrict__ out, int nDst)
{
  const int node = blockIdx.x * 4 + (threadIdx.x >> 6);
  if (node >= nDst) return;
  const int lane = threadIdx.x & 63;
  const bool act = lane < 52;                 // 52*8 = 416 dims
  float a[8];
  if (act) {
    ushort8 v = *(const ushort8*)(h + (size_t)node * 416 + lane * 8);
    #pragma unroll
    for (int j = 0; j < 8; ++j) a[j] = bf2f(v[j]);
  } else {
    #pragma unroll
    for (int j = 0; j < 8; ++j) a[j] = 0.f;
  }
  const int e0 = indptr[node], e1 = indptr[node + 1];
  int e = e0;
  for (; e + 2 <= e1; e += 2) {
    const int s0 = esrc[e], s1 = esrc[e + 1];
    const float w0 = ew[e], w1 = ew[e + 1];
    if (act) {
      ushort8 v0 = *(const ushort8*)(h + (size_t)s0 * 416 + lane * 8);
      ushort8 v1 = *(const ushort8*)(h + (size_t)s1 * 416 + lane * 8);
      #pragma unroll
      for (int j = 0; j < 8; ++j) a[j] += bf2f(v0[j]) * w0 + bf2f(v1[j]) * w1;
    }
  }
  if (e < e1) {
    const int s = esrc[e];
    const float w = ew[e];
    if (act) {
      ushort8 v = *(const ushort8*)(h + (size_t)s * 416 + lane * 8);
      #pragma unroll
      for (int j = 0; j < 8; ++j) a[j] += bf2f(v[j]) * w;
    }
  }
  const float inv = 1.f / ((float)(e1 - e0) + 1.f);
  if (act) {
    ushort8 o;
    #pragma unroll
    for (int j = 0; j < 8; ++j) o[j] = f2bf(a[j] * inv);
    *(ushort8*)(out + (size_t)node * 416 + lane * 8) = o;
  }
}

// ---------------- batchnorm + domain head ----------------
__global__ void bn_stats(const float* __restrict__ d, float* __restrict__ stats, int rows) {
  int lane = threadIdx.x & 63;
  int wid = (blockIdx.x * blockDim.x + threadIdx.x) >> 6;
  int nw = (gridDim.x * blockDim.x) >> 6;
  if (lane >= 50) return;
  float s = 0.f, s2 = 0.f;
  for (int r = wid; r < rows; r += nw) {
    float v = d[r * 50 + lane];
    s += v; s2 += v * v;
  }
  atomicAdd(&stats[lane], s);
  atomicAdd(&stats[50 + lane], s2);
}

__global__ void bn_final(const float* __restrict__ stats, const float* __restrict__ gamma,
                         const float* __restrict__ beta, float* __restrict__ ss, int rows) {
  int c = threadIdx.x;
  if (c >= 50) return;
  float mu = stats[c] / rows;
  float var = stats[50 + c] / rows - mu * mu;
  float inv = rsqrtf(var + 1e-5f);
  float sc = gamma[c] * inv;
  ss[c] = sc;
  ss[50 + c] = beta[c] - mu * sc;
}

__global__ void domain_head(const float* __restrict__ d, const float* __restrict__ ss,
                            const float* __restrict__ Wd2, const float* __restrict__ bd2,
                            float* __restrict__ out, int rows) {
  int r = blockIdx.x * 256 + threadIdx.x;
  if (r >= rows) return;
  float o0 = bd2[0], o1 = bd2[1];
  const float* dr = d + (size_t)r * 50;
  #pragma unroll 10
  for (int c = 0; c < 50; ++c) {
    float v = dr[c] * ss[c] + ss[50 + c];
    v = fmaxf(v, 0.f);
    o0 += v * Wd2[c];
    o1 += v * Wd2[50 + c];
  }
  out[r * 2]     = o0;
  out[r * 2 + 1] = o1;
}

// ---------------- launch ----------------
extern "C" void kernel_launch(void* const* d_in, const int* in_sizes, int n_in,
                              void* d_out, int out_size, void* d_ws, size_t ws_size,
                              hipStream_t stream)
{
  const float* x    = (const float*)d_in[0];
  const float* wall = (const float*)d_in[1];
  const float* Wsh  = (const float*)d_in[2];
  const float* bsh  = (const float*)d_in[3];
  const float* Whu  = (const float*)d_in[4];
  const float* bhu  = (const float*)d_in[5];
  const float* Wmo  = (const float*)d_in[6];
  const float* bmo  = (const float*)d_in[7];
  const float* Wn1  = (const float*)d_in[8];
  const float* bn1  = (const float*)d_in[9];
  const float* Wn2  = (const float*)d_in[10];
  const float* bn2  = (const float*)d_in[11];
  const float* Wlin = (const float*)d_in[12];
  const float* blin = (const float*)d_in[13];
  const float* Wd1  = (const float*)d_in[14];
  const float* bd1  = (const float*)d_in[15];
  const float* gamma= (const float*)d_in[16];
  const float* beta = (const float*)d_in[17];
  const float* Wd2  = (const float*)d_in[18];
  const float* bd2  = (const float*)d_in[19];
  const int* src1 = (const int*)d_in[20];
  const int* dst1 = (const int*)d_in[21];
  const int* eid1 = (const int*)d_in[22];
  const int* src2 = (const int*)d_in[23];
  const int* dst2 = (const int*)d_in[24];
  const int* eid2 = (const int*)d_in[25];

  char* ws = (char*)d_ws;
  unsigned short* h    = (unsigned short*)(ws);                    // [60000][416] bf16
  unsigned short* hn1  = (unsigned short*)(ws + 49920000ULL);      // [30000][416]
  unsigned short* h1   = (unsigned short*)(ws + 74880000ULL);      // [30000][416]
  unsigned short* hn2  = (unsigned short*)(ws + 99840000ULL);      // [15000][416]
  unsigned short* h2   = (unsigned short*)(ws + 112320000ULL);     // [15000][416]
  float* d_raw         = (float*)(ws + 124800000ULL);              // [15000][50] f32
  unsigned short* WCf  = (unsigned short*)(ws + 127800000ULL);     // 63*16384 ushorts
  unsigned short* WN1f = (unsigned short*)(ws + 129864384ULL);     // 13*16384
  unsigned short* WN2f = (unsigned short*)(ws + 130290368ULL);
  unsigned short* WHf  = (unsigned short*)(ws + 130716352ULL);
  float* b3      = (float*)(ws + 131142336ULL);
  float* bhead   = (float*)(ws + 131144384ULL);
  int*   cnt1    = (int*)(ws + 131146432ULL);
  int*   indptr1 = (int*)(ws + 131266496ULL);
  int*   fill1   = (int*)(ws + 131386560ULL);
  int*   esrc1   = (int*)(ws + 131506624ULL);
  float* ew1     = (float*)(ws + 135346624ULL);
  int*   cnt2    = (int*)(ws + 139186624ULL);
  int*   indptr2 = (int*)(ws + 139246688ULL);
  int*   fill2   = (int*)(ws + 139306752ULL);
  int*   esrc2   = (int*)(ws + 139366816ULL);
  float* ew2     = (float*)(ws + 141286816ULL);
  float* stats   = (float*)(ws + 143206816ULL);
  float* ssb     = (float*)(ws + 143207328ULL);

  const int E1 = 960000, E2 = 480000;
  const int N0 = 60000, N1 = 30000, N2 = 15000;

  // weight prep (fragment-order B) + biases
  build_bfrag<<<(63 * 16384 + 255) / 256, 256, 0, stream>>>(Wsh, Whu, Wmo, WCf, 63, 0, 400, 2000);
  build_bfrag<<<(13 * 16384 + 255) / 256, 256, 0, stream>>>(Wn1, nullptr, nullptr, WN1f, 13, 1, 400, 400);
  build_bfrag<<<(13 * 16384 + 255) / 256, 256, 0, stream>>>(Wn2, nullptr, nullptr, WN2f, 13, 1, 400, 400);
  build_bfrag<<<(13 * 16384 + 255) / 256, 256, 0, stream>>>(Wlin, Wd1, nullptr, WHf, 13, 2, 70, 400);
  build_bias3<<<2, 256, 0, stream>>>(bsh, bhu, bmo, b3);
  build_bhead<<<1, 512, 0, stream>>>(blin, bd1, bhead);

  (void)hipMemsetAsync(cnt1, 0, 120000, stream);
  (void)hipMemsetAsync(fill1, 0, 120000, stream);
  (void)hipMemsetAsync(cnt2, 0, 60000, stream);
  (void)hipMemsetAsync(fill2, 0, 60000, stream);
  (void)hipMemsetAsync(stats, 0, 400, stream);

  // stage 1: h = bf16(x @ Wcat.T + b3)  [60000][416]
  gemm1024<0, 0><<<469, 1024, 0, stream>>>(x, WCf, b3, h, nullptr, N0, 2000, 2000, 63, 400);

  // GNN layer 1
  count_deg<<<(E1 + 255) / 256, 256, 0, stream>>>(dst1, cnt1, E1);
  scan_indptr<<<1, 1024, 0, stream>>>(cnt1, indptr1, N1);
  fill_csr<<<(E1 + 255) / 256, 256, 0, stream>>>(src1, dst1, eid1, wall, indptr1, fill1, esrc1, ew1, E1);
  seg_mean_bf<<<N1 / 4, 256, 0, stream>>>(h, indptr1, esrc1, ew1, hn1, N1);
  gemm1024<1, 0><<<235, 1024, 0, stream>>>(hn1, WN1f, bn1, h1, nullptr, N1, 416, 416, 13, 400);

  // GNN layer 2
  count_deg<<<(E2 + 255) / 256, 256, 0, stream>>>(dst2, cnt2, E2);
  scan_indptr<<<1, 1024, 0, stream>>>(cnt2, indptr2, N2);
  fill_csr<<<(E2 + 255) / 256, 256, 0, stream>>>(src2, dst2, eid2, wall, indptr2, fill2, esrc2, ew2, E2);
  seg_mean_bf<<<N2 / 4, 256, 0, stream>>>(h1, indptr2, esrc2, ew2, hn2, N2);
  gemm1024<1, 0><<<118, 1024, 0, stream>>>(hn2, WN2f, bn2, h2, nullptr, N2, 416, 416, 13, 400);

  // fused heads: cols 0..19 -> h_x (d_out), 20..69 -> d_raw
  float* out_hx  = (float*)d_out;            // 15000 x 20
  float* out_dom = (float*)d_out + 300000;   // 15000 x 2
  gemm1024<1, 1><<<118, 1024, 0, stream>>>(h2, WHf, bhead, out_hx, d_raw, N2, 416, 416, 13, 70);

  bn_stats<<<128, 256, 0, stream>>>(d_raw, stats, N2);
  bn_final<<<1, 64, 0, stream>>>(stats, gamma, beta, ssb, N2);
  domain_head<<<(N2 + 255) / 256, 256, 0, stream>>>(d_raw, ssb, Wd2, bd2, out_dom, N2);
}

// Round 6
// 756.117 us; speedup vs baseline: 6.4255x; 6.4255x over previous
//
#include <hip/hip_runtime.h>
#include <stdint.h>
#include <stddef.h>

typedef short bf16x8 __attribute__((ext_vector_type(8)));
typedef unsigned short ushort8 __attribute__((ext_vector_type(8)));
typedef float f32x4 __attribute__((ext_vector_type(4)));

__device__ __forceinline__ unsigned short f2bf(float f) {
  union { float f; unsigned int u; } v; v.f = f;
  unsigned int r = v.u + 0x7FFFu + ((v.u >> 16) & 1u);  // RNE
  return (unsigned short)(r >> 16);
}
__device__ __forceinline__ float bf2f(unsigned short u) {
  union { unsigned int u; float f; } v; v.u = ((unsigned int)u) << 16; return v.f;
}

// ---------------- B fragment-order builder ----------------
// For K-step t, col-group g(0..31), lane(0..63), elem e(0..7):
//   idx = ((t*32 + g)*64 + lane)*8 + e   [16384 ushorts per K-step]
//   col = g*16 + (lane&15);  k = t*32 + (lane>>4)*8 + e
// mode 0: cat-K (W0 400x1000, W1 400x500, W2 400x500); mode 1: W0 [N x Kr];
// mode 2: head (W0=Wlin 20x400, W1=Wd1 50x400)
__global__ void build_bfrag(const float* __restrict__ W0, const float* __restrict__ W1,
                            const float* __restrict__ W2, unsigned short* __restrict__ out,
                            int ksteps, int mode, int N, int Kr)
{
  int idx = blockIdx.x * 256 + threadIdx.x;
  int total = ksteps * 16384;
  if (idx >= total) return;
  int t = idx >> 14;
  int rem = idx & 16383;
  int e = rem & 7;
  int chunk = rem >> 3;
  int lane = chunk & 63;
  int g = chunk >> 6;
  int col = g * 16 + (lane & 15);
  int k = t * 32 + ((lane >> 4) << 3) + e;
  float v = 0.f;
  if (mode == 0) {
    if (col < 400 && k < 2000) {
      if (k < 1000)      v = W0[col * 1000 + k];
      else if (k < 1500) v = W1[col * 500 + (k - 1000)];
      else               v = W2[col * 500 + (k - 1500)];
    }
  } else if (mode == 1) {
    if (col < N && k < Kr) v = W0[col * Kr + k];
  } else {
    if (k < 400) {
      if (col < 20)      v = W0[col * 400 + k];
      else if (col < 70) v = W1[(col - 20) * 400 + k];
    }
  }
  out[idx] = f2bf(v);
}

__global__ void build_bias3(const float* a, const float* b, const float* c, float* o) {
  int i = blockIdx.x * 256 + threadIdx.x;
  if (i < 416) o[i] = (i < 400) ? (a[i] + b[i] + c[i]) : 0.f;
}
__global__ void build_bhead(const float* blin, const float* bd1, float* o) {
  int i = threadIdx.x;
  if (i < 512) o[i] = (i < 20) ? blin[i] : ((i < 70) ? bd1[i - 20] : 0.f);
}

// ---------------- MFMA GEMM: 64x512 block, 256 thr = 4 waves (1M x 4N) ----------------
// Wave tile 64x128 (mi=4, ni=8), acc in AGPRs. A: LDS dbuf pad-36, 2-step reg
// prefetch via two NAMED staging sets (hand-2-unrolled loop, no runtime set idx).
// B: single captured bb[8] (static idx), loaded fragment-order from global (L2).
// ksteps must be ODD. AMODE 0: A f32 (k-guarded); AMODE 1: A bf16 stride Astride.
// OMODE 0: C bf16 [M][416]; OMODE 1: split f32 (col<20 -> Cv[M][20], 20..69 -> C2[M][50]).
template<int AMODE, int OMODE>
__global__ __launch_bounds__(256, 2) void gemm256(
    const void* __restrict__ Av, const unsigned short* __restrict__ Bf,
    const float* __restrict__ bias, void* __restrict__ Cv, float* __restrict__ C2,
    int M, int Kreal, int Astride, int ksteps, int Nreal)
{
  __shared__ unsigned short As[2][64][36];
  const int tid = threadIdx.x;
  const int lane = tid & 63;
  const int wc = tid >> 6;            // 0..3
  const int rowBase = blockIdx.x * 64;
  const int sRow = tid >> 2;          // 0..63
  const int sC = (tid & 3) << 3;      // 0,8,16,24
  const int aRow = rowBase + sRow;
  const bool aOK = aRow < M;
  const int fr = lane & 15;
  const int fq = lane >> 4;

  const float* Af = (const float*)Av;
  const unsigned short* Ah = (const unsigned short*)Av;
  const unsigned short* bWave = Bf + ((size_t)(wc * 8) * 64 + lane) * 8;

  f32x4 acc[4][8] = {};
  f32x4 a0lo, a0hi, a1lo, a1hi;   // AMODE0 staging sets (named, no runtime select)
  ushort8 ah0, ah1;               // AMODE1 staging sets
  ushort8 bb[8];                  // B frags, static indices only

  auto loadB = [&](int t) {
    const unsigned short* bp = bWave + (size_t)t * 16384;
    #pragma unroll
    for (int ni = 0; ni < 8; ++ni) bb[ni] = *(const ushort8*)(bp + ni * 512);
  };
  auto loadA0 = [&](int t) {
    const int k0 = t * 32 + sC;
    if (AMODE == 0) {
      if (aOK && (k0 + 4) <= Kreal) a0lo = *(const f32x4*)(Af + (size_t)aRow * Astride + k0);
      else { a0lo[0]=0.f; a0lo[1]=0.f; a0lo[2]=0.f; a0lo[3]=0.f; }
      if (aOK && (k0 + 8) <= Kreal) a0hi = *(const f32x4*)(Af + (size_t)aRow * Astride + k0 + 4);
      else { a0hi[0]=0.f; a0hi[1]=0.f; a0hi[2]=0.f; a0hi[3]=0.f; }
    } else {
      if (aOK) ah0 = *(const ushort8*)(Ah + (size_t)aRow * Astride + k0);
      else { ah0[0]=0; ah0[1]=0; ah0[2]=0; ah0[3]=0; ah0[4]=0; ah0[5]=0; ah0[6]=0; ah0[7]=0; }
    }
  };
  auto loadA1 = [&](int t) {
    const int k0 = t * 32 + sC;
    if (AMODE == 0) {
      if (aOK && (k0 + 4) <= Kreal) a1lo = *(const f32x4*)(Af + (size_t)aRow * Astride + k0);
      else { a1lo[0]=0.f; a1lo[1]=0.f; a1lo[2]=0.f; a1lo[3]=0.f; }
      if (aOK && (k0 + 8) <= Kreal) a1hi = *(const f32x4*)(Af + (size_t)aRow * Astride + k0 + 4);
      else { a1hi[0]=0.f; a1hi[1]=0.f; a1hi[2]=0.f; a1hi[3]=0.f; }
    } else {
      if (aOK) ah1 = *(const ushort8*)(Ah + (size_t)aRow * Astride + k0);
      else { ah1[0]=0; ah1[1]=0; ah1[2]=0; ah1[3]=0; ah1[4]=0; ah1[5]=0; ah1[6]=0; ah1[7]=0; }
    }
  };
  auto writeA0 = [&](int buf) {
    ushort8 w;
    if (AMODE == 0) {
      w[0]=f2bf(a0lo[0]); w[1]=f2bf(a0lo[1]); w[2]=f2bf(a0lo[2]); w[3]=f2bf(a0lo[3]);
      w[4]=f2bf(a0hi[0]); w[5]=f2bf(a0hi[1]); w[6]=f2bf(a0hi[2]); w[7]=f2bf(a0hi[3]);
    } else w = ah0;
    *(ushort8*)&As[buf][sRow][sC] = w;
  };
  auto writeA1 = [&](int buf) {
    ushort8 w;
    if (AMODE == 0) {
      w[0]=f2bf(a1lo[0]); w[1]=f2bf(a1lo[1]); w[2]=f2bf(a1lo[2]); w[3]=f2bf(a1lo[3]);
      w[4]=f2bf(a1hi[0]); w[5]=f2bf(a1hi[1]); w[6]=f2bf(a1hi[2]); w[7]=f2bf(a1hi[3]);
    } else w = ah1;
    *(ushort8*)&As[buf][sRow][sC] = w;
  };
  auto compute = [&](int buf) {
    bf16x8 af[4];
    #pragma unroll
    for (int mi = 0; mi < 4; ++mi)
      af[mi] = *(const bf16x8*)&As[buf][(mi << 4) + fr][fq << 3];
    #pragma unroll
    for (int ni = 0; ni < 8; ++ni) {
      bf16x8 bv;
      #pragma unroll
      for (int j = 0; j < 8; ++j) bv[j] = (short)bb[ni][j];
      #pragma unroll
      for (int mi = 0; mi < 4; ++mi)
        acc[mi][ni] = __builtin_amdgcn_mfma_f32_16x16x32_bf16(af[mi], bv, acc[mi][ni], 0, 0, 0);
    }
  };

  const int ksm1 = ksteps - 1;
  // prologue: buf0<-A(0); bb<-B(0); set1<-A(1); set0<-A(2)
  loadA0(0);
  loadB(0);
  loadA1(1 < ksm1 ? 1 : ksm1);
  writeA0(0);
  __syncthreads();
  loadA0(2 < ksm1 ? 2 : ksm1);

  for (int t = 0; t + 1 < ksteps; t += 2) {
    // step t: As[0], B(t)
    compute(0);
    loadB(t + 1);
    writeA1(1);                               // A(t+1) -> As[1]
    __syncthreads();
    loadA1(t + 3 < ksm1 ? t + 3 : ksm1);
    // step t+1: As[1], B(t+1)
    compute(1);
    loadB(t + 2 < ksm1 ? t + 2 : ksm1);
    writeA0(0);                               // A(t+2) -> As[0]
    __syncthreads();
    loadA0(t + 4 < ksm1 ? t + 4 : ksm1);
  }
  // tail step ksteps-1: As[0], B(ksteps-1)
  compute(0);

  // epilogue: C/D layout col=lane&15, row=(lane>>4)*4+r [m89]; wave tile = all 64 rows
  #pragma unroll
  for (int mi = 0; mi < 4; ++mi) {
    const int row0 = rowBase + (mi << 4) + (fq << 2);
    #pragma unroll
    for (int ni = 0; ni < 8; ++ni) {
      const int col = (wc << 7) + (ni << 4) + fr;
      if (OMODE == 0) {
        if (col < 416) {
          unsigned short* C = (unsigned short*)Cv;
          const float bv = (col < Nreal) ? bias[col] : 0.f;
          #pragma unroll
          for (int r = 0; r < 4; ++r) {
            const int row = row0 + r;
            if (row < M) C[(size_t)row * 416 + col] =
                (col < Nreal) ? f2bf(acc[mi][ni][r] + bv) : (unsigned short)0;
          }
        }
      } else {
        if (col < 70) {
          const float bv = bias[col];
          #pragma unroll
          for (int r = 0; r < 4; ++r) {
            const int row = row0 + r;
            if (row < M) {
              float v = acc[mi][ni][r] + bv;
              if (col < 20) ((float*)Cv)[(size_t)row * 20 + col] = v;
              else          C2[(size_t)row * 50 + (col - 20)] = v;
            }
          }
        }
      }
    }
  }
}

// ---------------- CSR build ----------------
__global__ void count_deg(const int* __restrict__ dst, int* __restrict__ cnt, int E) {
  int e = blockIdx.x * 256 + threadIdx.x;
  if (e < E) atomicAdd(&cnt[dst[e]], 1);
}

__global__ void scan_indptr(const int* __restrict__ cnt, int* __restrict__ indptr, int n) {
  __shared__ int sh[1024];
  __shared__ int carrySh;
  const int t = threadIdx.x;
  if (t == 0) carrySh = 0;
  __syncthreads();
  for (int base = 0; base < n; base += 8192) {
    int v[8]; int tsum = 0;
    #pragma unroll
    for (int i = 0; i < 8; ++i) {
      int idx = base + t * 8 + i;
      v[i] = (idx < n) ? cnt[idx] : 0;
      tsum += v[i];
    }
    sh[t] = tsum; __syncthreads();
    for (int off = 1; off < 1024; off <<= 1) {
      int add = (t >= off) ? sh[t - off] : 0;
      __syncthreads();
      sh[t] += add;
      __syncthreads();
    }
    int excl = carrySh + sh[t] - tsum;
    #pragma unroll
    for (int i = 0; i < 8; ++i) {
      int idx = base + t * 8 + i;
      if (idx < n) indptr[idx] = excl;
      excl += v[i];
    }
    __syncthreads();
    if (t == 1023) carrySh += sh[1023];
    __syncthreads();
  }
  if (t == 0) indptr[n] = carrySh;
}

__global__ void fill_csr(const int* __restrict__ src, const int* __restrict__ dst,
                         const int* __restrict__ eid, const float* __restrict__ wall,
                         const int* __restrict__ indptr, int* __restrict__ fillc,
                         int* __restrict__ esrc, float* __restrict__ ew, int E)
{
  int e = blockIdx.x * 256 + threadIdx.x;
  if (e >= E) return;
  int d = dst[e];
  int pos = atomicAdd(&fillc[d], 1);
  int slot = indptr[d] + pos;
  esrc[slot] = src[e];
  ew[slot] = wall[eid[e]];
}

// ---------------- segment mean-aggregate (bf16 in/out, stride 416) ----------------
__global__ __launch_bounds__(256) void seg_mean_bf(
    const unsigned short* __restrict__ h, const int* __restrict__ indptr,
    const int* __restrict__ esrc, const float* __restrict__ ew,
    unsigned short* __restrict__ out, int nDst)
{
  const int node = blockIdx.x * 4 + (threadIdx.x >> 6);
  if (node >= nDst) return;
  const int lane = threadIdx.x & 63;
  const bool act = lane < 52;                 // 52*8 = 416 dims
  float a[8];
  if (act) {
    ushort8 v = *(const ushort8*)(h + (size_t)node * 416 + lane * 8);
    #pragma unroll
    for (int j = 0; j < 8; ++j) a[j] = bf2f(v[j]);
  } else {
    #pragma unroll
    for (int j = 0; j < 8; ++j) a[j] = 0.f;
  }
  const int e0 = indptr[node], e1 = indptr[node + 1];
  int e = e0;
  for (; e + 2 <= e1; e += 2) {
    const int s0 = esrc[e], s1 = esrc[e + 1];
    const float w0 = ew[e], w1 = ew[e + 1];
    if (act) {
      ushort8 v0 = *(const ushort8*)(h + (size_t)s0 * 416 + lane * 8);
      ushort8 v1 = *(const ushort8*)(h + (size_t)s1 * 416 + lane * 8);
      #pragma unroll
      for (int j = 0; j < 8; ++j) a[j] += bf2f(v0[j]) * w0 + bf2f(v1[j]) * w1;
    }
  }
  if (e < e1) {
    const int s = esrc[e];
    const float w = ew[e];
    if (act) {
      ushort8 v = *(const ushort8*)(h + (size_t)s * 416 + lane * 8);
      #pragma unroll
      for (int j = 0; j < 8; ++j) a[j] += bf2f(v[j]) * w;
    }
  }
  const float inv = 1.f / ((float)(e1 - e0) + 1.f);
  if (act) {
    ushort8 o;
    #pragma unroll
    for (int j = 0; j < 8; ++j) o[j] = f2bf(a[j] * inv);
    *(ushort8*)(out + (size_t)node * 416 + lane * 8) = o;
  }
}

// ---------------- batchnorm + domain head ----------------
__global__ void bn_stats(const float* __restrict__ d, float* __restrict__ stats, int rows) {
  int lane = threadIdx.x & 63;
  int wid = (blockIdx.x * blockDim.x + threadIdx.x) >> 6;
  int nw = (gridDim.x * blockDim.x) >> 6;
  if (lane >= 50) return;
  float s = 0.f, s2 = 0.f;
  for (int r = wid; r < rows; r += nw) {
    float v = d[r * 50 + lane];
    s += v; s2 += v * v;
  }
  atomicAdd(&stats[lane], s);
  atomicAdd(&stats[50 + lane], s2);
}

__global__ void bn_final(const float* __restrict__ stats, const float* __restrict__ gamma,
                         const float* __restrict__ beta, float* __restrict__ ss, int rows) {
  int c = threadIdx.x;
  if (c >= 50) return;
  float mu = stats[c] / rows;
  float var = stats[50 + c] / rows - mu * mu;
  float inv = rsqrtf(var + 1e-5f);
  float sc = gamma[c] * inv;
  ss[c] = sc;
  ss[50 + c] = beta[c] - mu * sc;
}

__global__ void domain_head(const float* __restrict__ d, const float* __restrict__ ss,
                            const float* __restrict__ Wd2, const float* __restrict__ bd2,
                            float* __restrict__ out, int rows) {
  int r = blockIdx.x * 256 + threadIdx.x;
  if (r >= rows) return;
  float o0 = bd2[0], o1 = bd2[1];
  const float* dr = d + (size_t)r * 50;
  #pragma unroll 10
  for (int c = 0; c < 50; ++c) {
    float v = dr[c] * ss[c] + ss[50 + c];
    v = fmaxf(v, 0.f);
    o0 += v * Wd2[c];
    o1 += v * Wd2[50 + c];
  }
  out[r * 2]     = o0;
  out[r * 2 + 1] = o1;
}

// ---------------- launch ----------------
extern "C" void kernel_launch(void* const* d_in, const int* in_sizes, int n_in,
                              void* d_out, int out_size, void* d_ws, size_t ws_size,
                              hipStream_t stream)
{
  const float* x    = (const float*)d_in[0];
  const float* wall = (const float*)d_in[1];
  const float* Wsh  = (const float*)d_in[2];
  const float* bsh  = (const float*)d_in[3];
  const float* Whu  = (const float*)d_in[4];
  const float* bhu  = (const float*)d_in[5];
  const float* Wmo  = (const float*)d_in[6];
  const float* bmo  = (const float*)d_in[7];
  const float* Wn1  = (const float*)d_in[8];
  const float* bn1  = (const float*)d_in[9];
  const float* Wn2  = (const float*)d_in[10];
  const float* bn2  = (const float*)d_in[11];
  const float* Wlin = (const float*)d_in[12];
  const float* blin = (const float*)d_in[13];
  const float* Wd1  = (const float*)d_in[14];
  const float* bd1  = (const float*)d_in[15];
  const float* gamma= (const float*)d_in[16];
  const float* beta = (const float*)d_in[17];
  const float* Wd2  = (const float*)d_in[18];
  const float* bd2  = (const float*)d_in[19];
  const int* src1 = (const int*)d_in[20];
  const int* dst1 = (const int*)d_in[21];
  const int* eid1 = (const int*)d_in[22];
  const int* src2 = (const int*)d_in[23];
  const int* dst2 = (const int*)d_in[24];
  const int* eid2 = (const int*)d_in[25];

  char* ws = (char*)d_ws;
  unsigned short* h    = (unsigned short*)(ws);                    // [60000][416] bf16
  unsigned short* hn1  = (unsigned short*)(ws + 49920000ULL);      // [30000][416]
  unsigned short* h1   = (unsigned short*)(ws + 74880000ULL);      // [30000][416]
  unsigned short* hn2  = (unsigned short*)(ws + 99840000ULL);      // [15000][416]
  unsigned short* h2   = (unsigned short*)(ws + 112320000ULL);     // [15000][416]
  float* d_raw         = (float*)(ws + 124800000ULL);              // [15000][50] f32
  unsigned short* WCf  = (unsigned short*)(ws + 127800000ULL);     // 63*16384 ushorts
  unsigned short* WN1f = (unsigned short*)(ws + 129864384ULL);     // 13*16384
  unsigned short* WN2f = (unsigned short*)(ws + 130290368ULL);
  unsigned short* WHf  = (unsigned short*)(ws + 130716352ULL);
  float* b3      = (float*)(ws + 131142336ULL);
  float* bhead   = (float*)(ws + 131144384ULL);
  int*   cnt1    = (int*)(ws + 131146432ULL);
  int*   indptr1 = (int*)(ws + 131266496ULL);
  int*   fill1   = (int*)(ws + 131386560ULL);
  int*   esrc1   = (int*)(ws + 131506624ULL);
  float* ew1     = (float*)(ws + 135346624ULL);
  int*   cnt2    = (int*)(ws + 139186624ULL);
  int*   indptr2 = (int*)(ws + 139246688ULL);
  int*   fill2   = (int*)(ws + 139306752ULL);
  int*   esrc2   = (int*)(ws + 139366816ULL);
  float* ew2     = (float*)(ws + 141286816ULL);
  float* stats   = (float*)(ws + 143206816ULL);
  float* ssb     = (float*)(ws + 143207328ULL);

  const int E1 = 960000, E2 = 480000;
  const int N0 = 60000, N1 = 30000, N2 = 15000;

  // weight prep (fragment-order B) + biases
  build_bfrag<<<(63 * 16384 + 255) / 256, 256, 0, stream>>>(Wsh, Whu, Wmo, WCf, 63, 0, 400, 2000);
  build_bfrag<<<(13 * 16384 + 255) / 256, 256, 0, stream>>>(Wn1, nullptr, nullptr, WN1f, 13, 1, 400, 400);
  build_bfrag<<<(13 * 16384 + 255) / 256, 256, 0, stream>>>(Wn2, nullptr, nullptr, WN2f, 13, 1, 400, 400);
  build_bfrag<<<(13 * 16384 + 255) / 256, 256, 0, stream>>>(Wlin, Wd1, nullptr, WHf, 13, 2, 70, 400);
  build_bias3<<<2, 256, 0, stream>>>(bsh, bhu, bmo, b3);
  build_bhead<<<1, 512, 0, stream>>>(blin, bd1, bhead);

  (void)hipMemsetAsync(cnt1, 0, 120000, stream);
  (void)hipMemsetAsync(fill1, 0, 120000, stream);
  (void)hipMemsetAsync(cnt2, 0, 60000, stream);
  (void)hipMemsetAsync(fill2, 0, 60000, stream);
  (void)hipMemsetAsync(stats, 0, 400, stream);

  // stage 1: h = bf16(x @ Wcat.T + b3)  [60000][416]
  gemm256<0, 0><<<938, 256, 0, stream>>>(x, WCf, b3, h, nullptr, N0, 2000, 2000, 63, 400);

  // GNN layer 1
  count_deg<<<(E1 + 255) / 256, 256, 0, stream>>>(dst1, cnt1, E1);
  scan_indptr<<<1, 1024, 0, stream>>>(cnt1, indptr1, N1);
  fill_csr<<<(E1 + 255) / 256, 256, 0, stream>>>(src1, dst1, eid1, wall, indptr1, fill1, esrc1, ew1, E1);
  seg_mean_bf<<<N1 / 4, 256, 0, stream>>>(h, indptr1, esrc1, ew1, hn1, N1);
  gemm256<1, 0><<<469, 256, 0, stream>>>(hn1, WN1f, bn1, h1, nullptr, N1, 416, 416, 13, 400);

  // GNN layer 2
  count_deg<<<(E2 + 255) / 256, 256, 0, stream>>>(dst2, cnt2, E2);
  scan_indptr<<<1, 1024, 0, stream>>>(cnt2, indptr2, N2);
  fill_csr<<<(E2 + 255) / 256, 256, 0, stream>>>(src2, dst2, eid2, wall, indptr2, fill2, esrc2, ew2, E2);
  seg_mean_bf<<<N2 / 4, 256, 0, stream>>>(h1, indptr2, esrc2, ew2, hn2, N2);
  gemm256<1, 0><<<235, 256, 0, stream>>>(hn2, WN2f, bn2, h2, nullptr, N2, 416, 416, 13, 400);

  // fused heads: cols 0..19 -> h_x (d_out), 20..69 -> d_raw
  float* out_hx  = (float*)d_out;            // 15000 x 20
  float* out_dom = (float*)d_out + 300000;   // 15000 x 2
  gemm256<1, 1><<<235, 256, 0, stream>>>(h2, WHf, bhead, out_hx, d_raw, N2, 416, 416, 13, 70);

  bn_stats<<<128, 256, 0, stream>>>(d_raw, stats, N2);
  bn_final<<<1, 64, 0, stream>>>(stats, gamma, beta, ssb, N2);
  domain_head<<<(N2 + 255) / 256, 256, 0, stream>>>(d_raw, ssb, Wd2, bd2, out_dom, N2);
}

// Round 7
// 752.781 us; speedup vs baseline: 6.4540x; 1.0044x over previous
//
#include <hip/hip_runtime.h>
#include <stdint.h>
#include <stddef.h>

typedef short bf16x8 __attribute__((ext_vector_type(8)));
typedef unsigned short ushort8 __attribute__((ext_vector_type(8)));
typedef float f32x4 __attribute__((ext_vector_type(4)));

__device__ __forceinline__ unsigned short f2bf(float f) {
  union { float f; unsigned int u; } v; v.f = f;
  unsigned int r = v.u + 0x7FFFu + ((v.u >> 16) & 1u);  // RNE
  return (unsigned short)(r >> 16);
}
__device__ __forceinline__ float bf2f(unsigned short u) {
  union { unsigned int u; float f; } v; v.u = ((unsigned int)u) << 16; return v.f;
}

// ---------------- B fragment-order builder ----------------
// idx = ((t*32 + g)*64 + lane)*8 + e ; col = g*16 + (lane&15); k = t*32 + (lane>>4)*8 + e
__global__ void build_bfrag(const float* __restrict__ W0, const float* __restrict__ W1,
                            const float* __restrict__ W2, unsigned short* __restrict__ out,
                            int ksteps, int mode, int N, int Kr)
{
  int idx = blockIdx.x * 256 + threadIdx.x;
  int total = ksteps * 16384;
  if (idx >= total) return;
  int t = idx >> 14;
  int rem = idx & 16383;
  int e = rem & 7;
  int chunk = rem >> 3;
  int lane = chunk & 63;
  int g = chunk >> 6;
  int col = g * 16 + (lane & 15);
  int k = t * 32 + ((lane >> 4) << 3) + e;
  float v = 0.f;
  if (mode == 0) {
    if (col < 400 && k < 2000) {
      if (k < 1000)      v = W0[col * 1000 + k];
      else if (k < 1500) v = W1[col * 500 + (k - 1000)];
      else               v = W2[col * 500 + (k - 1500)];
    }
  } else if (mode == 1) {
    if (col < N && k < Kr) v = W0[col * Kr + k];
  } else {
    if (k < 400) {
      if (col < 20)      v = W0[col * 400 + k];
      else if (col < 70) v = W1[(col - 20) * 400 + k];
    }
  }
  out[idx] = f2bf(v);
}

__global__ void build_bias3(const float* a, const float* b, const float* c, float* o) {
  int i = blockIdx.x * 256 + threadIdx.x;
  if (i < 416) o[i] = (i < 400) ? (a[i] + b[i] + c[i]) : 0.f;
}
__global__ void build_bhead(const float* blin, const float* bd1, float* o) {
  int i = threadIdx.x;
  if (i < 512) o[i] = (i < 20) ? blin[i] : ((i < 70) ? bd1[i - 20] : 0.f);
}

// ---------------- MFMA GEMM: 64x512 block, 256 thr = 4 waves (1M x 4N) ----------------
// Wave tile 64x128 (mi=4, ni=8). A: LDS dbuf pad-36, 2-step reg prefetch (named sets).
// B: DOUBLE-BUFFERED reg frags bbA/bbB (named sets), loaded fragment-order from global,
// issued one step ahead of use. ksteps must be ODD.
template<int AMODE, int OMODE>
__global__ __launch_bounds__(256, 2) void gemm256(
    const void* __restrict__ Av, const unsigned short* __restrict__ Bf,
    const float* __restrict__ bias, void* __restrict__ Cv, float* __restrict__ C2,
    int M, int Kreal, int Astride, int ksteps, int Nreal)
{
  __shared__ unsigned short As[2][64][36];
  const int tid = threadIdx.x;
  const int lane = tid & 63;
  const int wc = tid >> 6;            // 0..3
  const int rowBase = blockIdx.x * 64;
  const int sRow = tid >> 2;          // 0..63
  const int sC = (tid & 3) << 3;      // 0,8,16,24
  const int aRow = rowBase + sRow;
  const bool aOK = aRow < M;
  const int fr = lane & 15;
  const int fq = lane >> 4;

  const float* Af = (const float*)Av;
  const unsigned short* Ah = (const unsigned short*)Av;
  const unsigned short* bWave = Bf + ((size_t)(wc * 8) * 64 + lane) * 8;

  f32x4 acc[4][8] = {};
  f32x4 a0lo, a0hi, a1lo, a1hi;   // A staging sets (named)
  ushort8 ah0, ah1;
  ushort8 bbA[8], bbB[8];         // B frag double-buffer (named sets, static idx)

  auto loadBA = [&](int t) {
    const unsigned short* bp = bWave + (size_t)t * 16384;
    #pragma unroll
    for (int ni = 0; ni < 8; ++ni) bbA[ni] = *(const ushort8*)(bp + ni * 512);
  };
  auto loadBB = [&](int t) {
    const unsigned short* bp = bWave + (size_t)t * 16384;
    #pragma unroll
    for (int ni = 0; ni < 8; ++ni) bbB[ni] = *(const ushort8*)(bp + ni * 512);
  };
  auto loadA0 = [&](int t) {
    const int k0 = t * 32 + sC;
    if (AMODE == 0) {
      if (aOK && (k0 + 4) <= Kreal) a0lo = *(const f32x4*)(Af + (size_t)aRow * Astride + k0);
      else { a0lo[0]=0.f; a0lo[1]=0.f; a0lo[2]=0.f; a0lo[3]=0.f; }
      if (aOK && (k0 + 8) <= Kreal) a0hi = *(const f32x4*)(Af + (size_t)aRow * Astride + k0 + 4);
      else { a0hi[0]=0.f; a0hi[1]=0.f; a0hi[2]=0.f; a0hi[3]=0.f; }
    } else {
      if (aOK) ah0 = *(const ushort8*)(Ah + (size_t)aRow * Astride + k0);
      else { ah0[0]=0; ah0[1]=0; ah0[2]=0; ah0[3]=0; ah0[4]=0; ah0[5]=0; ah0[6]=0; ah0[7]=0; }
    }
  };
  auto loadA1 = [&](int t) {
    const int k0 = t * 32 + sC;
    if (AMODE == 0) {
      if (aOK && (k0 + 4) <= Kreal) a1lo = *(const f32x4*)(Af + (size_t)aRow * Astride + k0);
      else { a1lo[0]=0.f; a1lo[1]=0.f; a1lo[2]=0.f; a1lo[3]=0.f; }
      if (aOK && (k0 + 8) <= Kreal) a1hi = *(const f32x4*)(Af + (size_t)aRow * Astride + k0 + 4);
      else { a1hi[0]=0.f; a1hi[1]=0.f; a1hi[2]=0.f; a1hi[3]=0.f; }
    } else {
      if (aOK) ah1 = *(const ushort8*)(Ah + (size_t)aRow * Astride + k0);
      else { ah1[0]=0; ah1[1]=0; ah1[2]=0; ah1[3]=0; ah1[4]=0; ah1[5]=0; ah1[6]=0; ah1[7]=0; }
    }
  };
  auto writeA0 = [&](int buf) {
    ushort8 w;
    if (AMODE == 0) {
      w[0]=f2bf(a0lo[0]); w[1]=f2bf(a0lo[1]); w[2]=f2bf(a0lo[2]); w[3]=f2bf(a0lo[3]);
      w[4]=f2bf(a0hi[0]); w[5]=f2bf(a0hi[1]); w[6]=f2bf(a0hi[2]); w[7]=f2bf(a0hi[3]);
    } else w = ah0;
    *(ushort8*)&As[buf][sRow][sC] = w;
  };
  auto writeA1 = [&](int buf) {
    ushort8 w;
    if (AMODE == 0) {
      w[0]=f2bf(a1lo[0]); w[1]=f2bf(a1lo[1]); w[2]=f2bf(a1lo[2]); w[3]=f2bf(a1lo[3]);
      w[4]=f2bf(a1hi[0]); w[5]=f2bf(a1hi[1]); w[6]=f2bf(a1hi[2]); w[7]=f2bf(a1hi[3]);
    } else w = ah1;
    *(ushort8*)&As[buf][sRow][sC] = w;
  };
  auto computeA = [&](int buf) {
    bf16x8 af[4];
    #pragma unroll
    for (int mi = 0; mi < 4; ++mi)
      af[mi] = *(const bf16x8*)&As[buf][(mi << 4) + fr][fq << 3];
    #pragma unroll
    for (int ni = 0; ni < 8; ++ni) {
      bf16x8 bv;
      #pragma unroll
      for (int j = 0; j < 8; ++j) bv[j] = (short)bbA[ni][j];
      #pragma unroll
      for (int mi = 0; mi < 4; ++mi)
        acc[mi][ni] = __builtin_amdgcn_mfma_f32_16x16x32_bf16(af[mi], bv, acc[mi][ni], 0, 0, 0);
    }
  };
  auto computeB = [&](int buf) {
    bf16x8 af[4];
    #pragma unroll
    for (int mi = 0; mi < 4; ++mi)
      af[mi] = *(const bf16x8*)&As[buf][(mi << 4) + fr][fq << 3];
    #pragma unroll
    for (int ni = 0; ni < 8; ++ni) {
      bf16x8 bv;
      #pragma unroll
      for (int j = 0; j < 8; ++j) bv[j] = (short)bbB[ni][j];
      #pragma unroll
      for (int mi = 0; mi < 4; ++mi)
        acc[mi][ni] = __builtin_amdgcn_mfma_f32_16x16x32_bf16(af[mi], bv, acc[mi][ni], 0, 0, 0);
    }
  };

  const int ksm1 = ksteps - 1;
  // prologue
  loadA0(0);
  loadBA(0);
  loadA1(1 < ksm1 ? 1 : ksm1);
  writeA0(0);
  __syncthreads();
  loadA0(2 < ksm1 ? 2 : ksm1);

  for (int t = 0; t + 1 < ksteps; t += 2) {
    // step t: As[0], bbA = B(t); prefetch B(t+1)
    loadBB(t + 1);
    computeA(0);
    writeA1(1);
    __syncthreads();
    loadA1(t + 3 < ksm1 ? t + 3 : ksm1);
    // step t+1: As[1], bbB = B(t+1); prefetch B(t+2)
    loadBA(t + 2);
    computeB(1);
    writeA0(0);
    __syncthreads();
    loadA0(t + 4 < ksm1 ? t + 4 : ksm1);
  }
  // tail step ksteps-1: As[0], bbA = B(ksteps-1)
  computeA(0);

  // epilogue: C/D layout col=lane&15, row=(lane>>4)*4+r [m89]
  #pragma unroll
  for (int mi = 0; mi < 4; ++mi) {
    const int row0 = rowBase + (mi << 4) + (fq << 2);
    #pragma unroll
    for (int ni = 0; ni < 8; ++ni) {
      const int col = (wc << 7) + (ni << 4) + fr;
      if (OMODE == 0) {
        if (col < 416) {
          unsigned short* C = (unsigned short*)Cv;
          const float bv = (col < Nreal) ? bias[col] : 0.f;
          #pragma unroll
          for (int r = 0; r < 4; ++r) {
            const int row = row0 + r;
            if (row < M) C[(size_t)row * 416 + col] =
                (col < Nreal) ? f2bf(acc[mi][ni][r] + bv) : (unsigned short)0;
          }
        }
      } else {
        if (col < 70) {
          const float bv = bias[col];
          #pragma unroll
          for (int r = 0; r < 4; ++r) {
            const int row = row0 + r;
            if (row < M) {
              float v = acc[mi][ni][r] + bv;
              if (col < 20) ((float*)Cv)[(size_t)row * 20 + col] = v;
              else          C2[(size_t)row * 50 + (col - 20)] = v;
            }
          }
        }
      }
    }
  }
}

// ---------------- CSR build (both layers fused) ----------------
__global__ void count_deg_all(const int* __restrict__ dst1, int* __restrict__ cnt1, int E1,
                              const int* __restrict__ dst2, int* __restrict__ cnt2, int E2)
{
  int e = blockIdx.x * 256 + threadIdx.x;
  if (e < E1) atomicAdd(&cnt1[dst1[e]], 1);
  else if (e < E1 + E2) atomicAdd(&cnt2[dst2[e - E1]], 1);
}

__device__ void scan_one(const int* __restrict__ cnt, int* __restrict__ indptr, int n,
                         int* sh, int* carrySh)
{
  const int t = threadIdx.x;
  if (t == 0) *carrySh = 0;
  __syncthreads();
  for (int base = 0; base < n; base += 8192) {
    int v[8]; int tsum = 0;
    #pragma unroll
    for (int i = 0; i < 8; ++i) {
      int idx = base + t * 8 + i;
      v[i] = (idx < n) ? cnt[idx] : 0;
      tsum += v[i];
    }
    sh[t] = tsum; __syncthreads();
    for (int off = 1; off < 1024; off <<= 1) {
      int add = (t >= off) ? sh[t - off] : 0;
      __syncthreads();
      sh[t] += add;
      __syncthreads();
    }
    int excl = *carrySh + sh[t] - tsum;
    #pragma unroll
    for (int i = 0; i < 8; ++i) {
      int idx = base + t * 8 + i;
      if (idx < n) indptr[idx] = excl;
      excl += v[i];
    }
    __syncthreads();
    if (t == 1023) *carrySh += sh[1023];
    __syncthreads();
  }
  if (t == 0) indptr[n] = *carrySh;
  __syncthreads();
}

__global__ void scan_indptr2(const int* __restrict__ c1, int* __restrict__ p1, int n1,
                             const int* __restrict__ c2, int* __restrict__ p2, int n2)
{
  __shared__ int sh[1024];
  __shared__ int carrySh;
  scan_one(c1, p1, n1, sh, &carrySh);
  scan_one(c2, p2, n2, sh, &carrySh);
}

__global__ void fill_csr_all(
    const int* __restrict__ src1, const int* __restrict__ dst1, const int* __restrict__ eid1,
    const int* __restrict__ indptr1, int* __restrict__ fill1, int* __restrict__ esrc1, float* __restrict__ ew1, int E1,
    const int* __restrict__ src2, const int* __restrict__ dst2, const int* __restrict__ eid2,
    const int* __restrict__ indptr2, int* __restrict__ fill2, int* __restrict__ esrc2, float* __restrict__ ew2, int E2,
    const float* __restrict__ wall)
{
  int e = blockIdx.x * 256 + threadIdx.x;
  if (e < E1) {
    int d = dst1[e];
    int pos = atomicAdd(&fill1[d], 1);
    int slot = indptr1[d] + pos;
    esrc1[slot] = src1[e];
    ew1[slot] = wall[eid1[e]];
  } else if (e < E1 + E2) {
    int e2 = e - E1;
    int d = dst2[e2];
    int pos = atomicAdd(&fill2[d], 1);
    int slot = indptr2[d] + pos;
    esrc2[slot] = src2[e2];
    ew2[slot] = wall[eid2[e2]];
  }
}

// ---------------- segment mean-aggregate (bf16, stride 416, 4-unrolled) ----------------
__global__ __launch_bounds__(256) void seg_mean_bf(
    const unsigned short* __restrict__ h, const int* __restrict__ indptr,
    const int* __restrict__ esrc, const float* __restrict__ ew,
    unsigned short* __restrict__ out, int nDst)
{
  const int node = blockIdx.x * 4 + (threadIdx.x >> 6);
  if (node >= nDst) return;
  const int lane = threadIdx.x & 63;
  const bool act = lane < 52;                 // 52*8 = 416 dims
  float a[8];
  if (act) {
    ushort8 v = *(const ushort8*)(h + (size_t)node * 416 + lane * 8);
    #pragma unroll
    for (int j = 0; j < 8; ++j) a[j] = bf2f(v[j]);
  } else {
    #pragma unroll
    for (int j = 0; j < 8; ++j) a[j] = 0.f;
  }
  const int e0 = indptr[node], e1 = indptr[node + 1];
  int e = e0;
  for (; e + 4 <= e1; e += 4) {
    const int s0 = esrc[e], s1 = esrc[e + 1], s2 = esrc[e + 2], s3 = esrc[e + 3];
    const float w0 = ew[e], w1 = ew[e + 1], w2 = ew[e + 2], w3 = ew[e + 3];
    if (act) {
      ushort8 v0 = *(const ushort8*)(h + (size_t)s0 * 416 + lane * 8);
      ushort8 v1 = *(const ushort8*)(h + (size_t)s1 * 416 + lane * 8);
      ushort8 v2 = *(const ushort8*)(h + (size_t)s2 * 416 + lane * 8);
      ushort8 v3 = *(const ushort8*)(h + (size_t)s3 * 416 + lane * 8);
      #pragma unroll
      for (int j = 0; j < 8; ++j)
        a[j] += (bf2f(v0[j]) * w0 + bf2f(v1[j]) * w1) + (bf2f(v2[j]) * w2 + bf2f(v3[j]) * w3);
    }
  }
  for (; e < e1; ++e) {
    const int s = esrc[e];
    const float w = ew[e];
    if (act) {
      ushort8 v = *(const ushort8*)(h + (size_t)s * 416 + lane * 8);
      #pragma unroll
      for (int j = 0; j < 8; ++j) a[j] += bf2f(v[j]) * w;
    }
  }
  const float inv = 1.f / ((float)(e1 - e0) + 1.f);
  if (act) {
    ushort8 o;
    #pragma unroll
    for (int j = 0; j < 8; ++j) o[j] = f2bf(a[j] * inv);
    *(ushort8*)(out + (size_t)node * 416 + lane * 8) = o;
  }
}

// ---------------- batchnorm stats + fused finalize/domain head ----------------
__global__ void bn_stats(const float* __restrict__ d, float* __restrict__ stats, int rows) {
  int lane = threadIdx.x & 63;
  int wid = (blockIdx.x * blockDim.x + threadIdx.x) >> 6;
  int nw = (gridDim.x * blockDim.x) >> 6;
  if (lane >= 50) return;
  float s = 0.f, s2 = 0.f;
  for (int r = wid; r < rows; r += nw) {
    float v = d[r * 50 + lane];
    s += v; s2 += v * v;
  }
  atomicAdd(&stats[lane], s);
  atomicAdd(&stats[50 + lane], s2);
}

__global__ void domain_head2(const float* __restrict__ d, const float* __restrict__ stats,
                             const float* __restrict__ gamma, const float* __restrict__ beta,
                             const float* __restrict__ Wd2, const float* __restrict__ bd2,
                             float* __restrict__ out, int rows)
{
  __shared__ float ss[100];
  const int t = threadIdx.x;
  if (t < 50) {
    float mu = stats[t] / rows;
    float var = stats[50 + t] / rows - mu * mu;
    float inv = rsqrtf(var + 1e-5f);
    float sc = gamma[t] * inv;
    ss[t] = sc;
    ss[50 + t] = beta[t] - mu * sc;
  }
  __syncthreads();
  int r = blockIdx.x * 256 + t;
  if (r >= rows) return;
  float o0 = bd2[0], o1 = bd2[1];
  const float* dr = d + (size_t)r * 50;
  #pragma unroll 10
  for (int c = 0; c < 50; ++c) {
    float v = dr[c] * ss[c] + ss[50 + c];
    v = fmaxf(v, 0.f);
    o0 += v * Wd2[c];
    o1 += v * Wd2[50 + c];
  }
  out[r * 2]     = o0;
  out[r * 2 + 1] = o1;
}

// ---------------- launch ----------------
extern "C" void kernel_launch(void* const* d_in, const int* in_sizes, int n_in,
                              void* d_out, int out_size, void* d_ws, size_t ws_size,
                              hipStream_t stream)
{
  const float* x    = (const float*)d_in[0];
  const float* wall = (const float*)d_in[1];
  const float* Wsh  = (const float*)d_in[2];
  const float* bsh  = (const float*)d_in[3];
  const float* Whu  = (const float*)d_in[4];
  const float* bhu  = (const float*)d_in[5];
  const float* Wmo  = (const float*)d_in[6];
  const float* bmo  = (const float*)d_in[7];
  const float* Wn1  = (const float*)d_in[8];
  const float* bn1  = (const float*)d_in[9];
  const float* Wn2  = (const float*)d_in[10];
  const float* bn2  = (const float*)d_in[11];
  const float* Wlin = (const float*)d_in[12];
  const float* blin = (const float*)d_in[13];
  const float* Wd1  = (const float*)d_in[14];
  const float* bd1  = (const float*)d_in[15];
  const float* gamma= (const float*)d_in[16];
  const float* beta = (const float*)d_in[17];
  const float* Wd2  = (const float*)d_in[18];
  const float* bd2  = (const float*)d_in[19];
  const int* src1 = (const int*)d_in[20];
  const int* dst1 = (const int*)d_in[21];
  const int* eid1 = (const int*)d_in[22];
  const int* src2 = (const int*)d_in[23];
  const int* dst2 = (const int*)d_in[24];
  const int* eid2 = (const int*)d_in[25];

  char* ws = (char*)d_ws;
  unsigned short* h    = (unsigned short*)(ws);                    // [60000][416] bf16
  unsigned short* hn1  = (unsigned short*)(ws + 49920000ULL);      // [30000][416]
  unsigned short* h1   = (unsigned short*)(ws + 74880000ULL);      // [30000][416]
  unsigned short* hn2  = (unsigned short*)(ws + 99840000ULL);      // [15000][416]
  unsigned short* h2   = (unsigned short*)(ws + 112320000ULL);     // [15000][416]
  float* d_raw         = (float*)(ws + 124800000ULL);              // [15000][50] f32
  unsigned short* WCf  = (unsigned short*)(ws + 127800000ULL);     // 63*16384 ushorts
  unsigned short* WN1f = (unsigned short*)(ws + 129864384ULL);     // 13*16384
  unsigned short* WN2f = (unsigned short*)(ws + 130290368ULL);
  unsigned short* WHf  = (unsigned short*)(ws + 130716352ULL);
  float* b3      = (float*)(ws + 131142336ULL);
  float* bhead   = (float*)(ws + 131144384ULL);
  int*   cnt1    = (int*)(ws + 131146432ULL);
  int*   indptr1 = (int*)(ws + 131266496ULL);
  int*   fill1   = (int*)(ws + 131386560ULL);
  int*   esrc1   = (int*)(ws + 131506624ULL);
  float* ew1     = (float*)(ws + 135346624ULL);
  int*   cnt2    = (int*)(ws + 139186624ULL);
  int*   indptr2 = (int*)(ws + 139246688ULL);
  int*   fill2   = (int*)(ws + 139306752ULL);
  int*   esrc2   = (int*)(ws + 139366816ULL);
  float* ew2     = (float*)(ws + 141286816ULL);
  float* stats   = (float*)(ws + 143206816ULL);

  const int E1 = 960000, E2 = 480000;
  const int N0 = 60000, N1 = 30000, N2 = 15000;

  // weight prep (fragment-order B) + biases
  build_bfrag<<<(63 * 16384 + 255) / 256, 256, 0, stream>>>(Wsh, Whu, Wmo, WCf, 63, 0, 400, 2000);
  build_bfrag<<<(13 * 16384 + 255) / 256, 256, 0, stream>>>(Wn1, nullptr, nullptr, WN1f, 13, 1, 400, 400);
  build_bfrag<<<(13 * 16384 + 255) / 256, 256, 0, stream>>>(Wn2, nullptr, nullptr, WN2f, 13, 1, 400, 400);
  build_bfrag<<<(13 * 16384 + 255) / 256, 256, 0, stream>>>(Wlin, Wd1, nullptr, WHf, 13, 2, 70, 400);
  build_bias3<<<2, 256, 0, stream>>>(bsh, bhu, bmo, b3);
  build_bhead<<<1, 512, 0, stream>>>(blin, bd1, bhead);

  (void)hipMemsetAsync(cnt1, 0, 120000, stream);
  (void)hipMemsetAsync(fill1, 0, 120000, stream);
  (void)hipMemsetAsync(cnt2, 0, 60000, stream);
  (void)hipMemsetAsync(fill2, 0, 60000, stream);
  (void)hipMemsetAsync(stats, 0, 400, stream);

  // CSR build (both layers, fused kernels) — independent of GEMM
  count_deg_all<<<(E1 + E2 + 255) / 256, 256, 0, stream>>>(dst1, cnt1, E1, dst2, cnt2, E2);
  scan_indptr2<<<1, 1024, 0, stream>>>(cnt1, indptr1, N1, cnt2, indptr2, N2);
  fill_csr_all<<<(E1 + E2 + 255) / 256, 256, 0, stream>>>(
      src1, dst1, eid1, indptr1, fill1, esrc1, ew1, E1,
      src2, dst2, eid2, indptr2, fill2, esrc2, ew2, E2, wall);

  // stage 1: h = bf16(x @ Wcat.T + b3)  [60000][416]
  gemm256<0, 0><<<938, 256, 0, stream>>>(x, WCf, b3, h, nullptr, N0, 2000, 2000, 63, 400);

  // GNN layer 1
  seg_mean_bf<<<N1 / 4, 256, 0, stream>>>(h, indptr1, esrc1, ew1, hn1, N1);
  gemm256<1, 0><<<469, 256, 0, stream>>>(hn1, WN1f, bn1, h1, nullptr, N1, 416, 416, 13, 400);

  // GNN layer 2
  seg_mean_bf<<<N2 / 4, 256, 0, stream>>>(h1, indptr2, esrc2, ew2, hn2, N2);
  gemm256<1, 0><<<235, 256, 0, stream>>>(hn2, WN2f, bn2, h2, nullptr, N2, 416, 416, 13, 400);

  // fused heads: cols 0..19 -> h_x (d_out), 20..69 -> d_raw
  float* out_hx  = (float*)d_out;            // 15000 x 20
  float* out_dom = (float*)d_out + 300000;   // 15000 x 2
  gemm256<1, 1><<<235, 256, 0, stream>>>(h2, WHf, bhead, out_hx, d_raw, N2, 416, 416, 13, 70);

  bn_stats<<<128, 256, 0, stream>>>(d_raw, stats, N2);
  domain_head2<<<(N2 + 255) / 256, 256, 0, stream>>>(d_raw, stats, gamma, beta, Wd2, bd2, out_dom, N2);
}

// Round 8
// 739.833 us; speedup vs baseline: 6.5670x; 1.0175x over previous
//
#include <hip/hip_runtime.h>
#include <stdint.h>
#include <stddef.h>

typedef short bf16x8 __attribute__((ext_vector_type(8)));
typedef unsigned short ushort8 __attribute__((ext_vector_type(8)));
typedef float f32x4 __attribute__((ext_vector_type(4)));

__device__ __forceinline__ unsigned short f2bf(float f) {
  union { float f; unsigned int u; } v; v.f = f;
  unsigned int r = v.u + 0x7FFFu + ((v.u >> 16) & 1u);  // RNE
  return (unsigned short)(r >> 16);
}
__device__ __forceinline__ float bf2f(unsigned short u) {
  union { unsigned int u; float f; } v; v.u = ((unsigned int)u) << 16; return v.f;
}

// ---------------- unified B fragment builder ----------------
// 32-k-step fragment layout: idx = ((t32*32 + g)*64 + lane)*8 + e
//   col = g*16 + (lane&15); k = t32*32 + (lane>>4)*8 + e
// Segments: WCf (64 steps, mode0 cat-K), WN1f (14, mode1 Wn1), WN2f (14, mode1 Wn2),
//           WHf (14, mode2 head Wlin+Wd1)
__global__ void build_all_bfrag(
    const float* __restrict__ Wsh, const float* __restrict__ Whu, const float* __restrict__ Wmo,
    const float* __restrict__ Wn1, const float* __restrict__ Wn2,
    const float* __restrict__ Wlin, const float* __restrict__ Wd1,
    unsigned short* __restrict__ WCf, unsigned short* __restrict__ WN1f,
    unsigned short* __restrict__ WN2f, unsigned short* __restrict__ WHf)
{
  const int s0 = 64 * 16384, s1 = s0 + 14 * 16384, s2 = s1 + 14 * 16384, s3 = s2 + 14 * 16384;
  int idx = blockIdx.x * 256 + threadIdx.x;
  if (idx >= s3) return;
  int mode, rel;
  unsigned short* out;
  if (idx < s0)      { mode = 0; rel = idx;      out = WCf;  }
  else if (idx < s1) { mode = 1; rel = idx - s0; out = WN1f; }
  else if (idx < s2) { mode = 3; rel = idx - s1; out = WN2f; }
  else               { mode = 2; rel = idx - s2; out = WHf;  }
  int t = rel >> 14;
  int rem = rel & 16383;
  int e = rem & 7;
  int chunk = rem >> 3;
  int lane = chunk & 63;
  int g = chunk >> 6;
  int col = g * 16 + (lane & 15);
  int k = t * 32 + ((lane >> 4) << 3) + e;
  float v = 0.f;
  if (mode == 0) {
    if (col < 400 && k < 2000) {
      if (k < 1000)      v = Wsh[col * 1000 + k];
      else if (k < 1500) v = Whu[col * 500 + (k - 1000)];
      else               v = Wmo[col * 500 + (k - 1500)];
    }
  } else if (mode == 1) {
    if (col < 400 && k < 400) v = Wn1[col * 400 + k];
  } else if (mode == 3) {
    if (col < 400 && k < 400) v = Wn2[col * 400 + k];
  } else {
    if (k < 400) {
      if (col < 20)      v = Wlin[col * 400 + k];
      else if (col < 70) v = Wd1[(col - 20) * 400 + k];
    }
  }
  out[rel] = f2bf(v);
}

__global__ void build_biases(const float* __restrict__ a, const float* __restrict__ b,
                             const float* __restrict__ c, const float* __restrict__ blin,
                             const float* __restrict__ bd1, float* __restrict__ b3,
                             float* __restrict__ bhead)
{
  int t = threadIdx.x;
  if (t < 416) b3[t] = (t < 400) ? (a[t] + b[t] + c[t]) : 0.f;
  if (t < 512) bhead[t] = (t < 20) ? blin[t] : ((t < 70) ? bd1[t - 20] : 0.f);
}

// ---------------- MFMA GEMM: 64x512 block, 512 thr = 8 waves (1M x 8N), BK=64 ----------------
// Wave tile 64x64 (mi=4, ni=4), acc[4][4]=64 regs. A: LDS dbuf [2][64][72], 2-step reg
// prefetch (named sets). B: bb[16] single-buffered (compiler pipelines reloads after last
// use inside the 64-MFMA window). One barrier per 64-k step.
template<int AMODE, int OMODE>
__global__ __launch_bounds__(512) void gemmk(
    const void* __restrict__ Av, const unsigned short* __restrict__ Bf,
    const float* __restrict__ bias, void* __restrict__ Cv, float* __restrict__ C2,
    int M, int Kreal, int Astride, int ksteps, int Nreal)
{
  __shared__ unsigned short As[2][64][72];
  const int tid = threadIdx.x;
  const int lane = tid & 63;
  const int wc = tid >> 6;            // 0..7
  const int rowBase = blockIdx.x * 64;
  const int sRow = tid >> 3;          // 0..63
  const int sC = (tid & 7) << 3;      // 0..56 step 8
  const int aRow = rowBase + sRow;
  const bool aOK = aRow < M;
  const int fr = lane & 15;
  const int fq = lane >> 4;

  const float* Af = (const float*)Av;
  const unsigned short* Ah = (const unsigned short*)Av;
  const unsigned short* bWave = Bf + ((size_t)(wc * 4) * 64 + lane) * 8;

  f32x4 acc[4][4] = {};
  f32x4 a0lo, a0hi, a1lo, a1hi;   // AMODE0 staging (named sets)
  ushort8 ah0, ah1;               // AMODE1 staging
  ushort8 bb[16];                 // B frags for one 64-k step (static idx)

  auto loadB = [&](int t) {
    const unsigned short* bp0 = bWave + (size_t)(2 * t) * 16384;
    const unsigned short* bp1 = bWave + (size_t)(2 * t + 1) * 16384;
    #pragma unroll
    for (int ni = 0; ni < 4; ++ni) bb[ni] = *(const ushort8*)(bp0 + ni * 512);
    #pragma unroll
    for (int ni = 0; ni < 4; ++ni) bb[4 + ni] = *(const ushort8*)(bp1 + ni * 512);
  };
  // note: bb[0..3] = kh0 frags, bb[4..7] = kh1 frags (per 64-k step)
  auto loadA0 = [&](int t) {
    const int k0 = t * 64 + sC;
    if (AMODE == 0) {
      if (aOK && (k0 + 4) <= Kreal) a0lo = *(const f32x4*)(Af + (size_t)aRow * Astride + k0);
      else { a0lo[0]=0.f; a0lo[1]=0.f; a0lo[2]=0.f; a0lo[3]=0.f; }
      if (aOK && (k0 + 8) <= Kreal) a0hi = *(const f32x4*)(Af + (size_t)aRow * Astride + k0 + 4);
      else { a0hi[0]=0.f; a0hi[1]=0.f; a0hi[2]=0.f; a0hi[3]=0.f; }
    } else {
      if (aOK && (k0 + 8) <= Kreal) ah0 = *(const ushort8*)(Ah + (size_t)aRow * Astride + k0);
      else { ah0[0]=0; ah0[1]=0; ah0[2]=0; ah0[3]=0; ah0[4]=0; ah0[5]=0; ah0[6]=0; ah0[7]=0; }
    }
  };
  auto loadA1 = [&](int t) {
    const int k0 = t * 64 + sC;
    if (AMODE == 0) {
      if (aOK && (k0 + 4) <= Kreal) a1lo = *(const f32x4*)(Af + (size_t)aRow * Astride + k0);
      else { a1lo[0]=0.f; a1lo[1]=0.f; a1lo[2]=0.f; a1lo[3]=0.f; }
      if (aOK && (k0 + 8) <= Kreal) a1hi = *(const f32x4*)(Af + (size_t)aRow * Astride + k0 + 4);
      else { a1hi[0]=0.f; a1hi[1]=0.f; a1hi[2]=0.f; a1hi[3]=0.f; }
    } else {
      if (aOK && (k0 + 8) <= Kreal) ah1 = *(const ushort8*)(Ah + (size_t)aRow * Astride + k0);
      else { ah1[0]=0; ah1[1]=0; ah1[2]=0; ah1[3]=0; ah1[4]=0; ah1[5]=0; ah1[6]=0; ah1[7]=0; }
    }
  };
  auto writeA0 = [&](int buf) {
    ushort8 w;
    if (AMODE == 0) {
      w[0]=f2bf(a0lo[0]); w[1]=f2bf(a0lo[1]); w[2]=f2bf(a0lo[2]); w[3]=f2bf(a0lo[3]);
      w[4]=f2bf(a0hi[0]); w[5]=f2bf(a0hi[1]); w[6]=f2bf(a0hi[2]); w[7]=f2bf(a0hi[3]);
    } else w = ah0;
    *(ushort8*)&As[buf][sRow][sC] = w;
  };
  auto writeA1 = [&](int buf) {
    ushort8 w;
    if (AMODE == 0) {
      w[0]=f2bf(a1lo[0]); w[1]=f2bf(a1lo[1]); w[2]=f2bf(a1lo[2]); w[3]=f2bf(a1lo[3]);
      w[4]=f2bf(a1hi[0]); w[5]=f2bf(a1hi[1]); w[6]=f2bf(a1hi[2]); w[7]=f2bf(a1hi[3]);
    } else w = ah1;
    *(ushort8*)&As[buf][sRow][sC] = w;
  };
  auto computeS = [&](int buf) {
    #pragma unroll
    for (int kh = 0; kh < 2; ++kh) {
      bf16x8 af[4];
      #pragma unroll
      for (int mi = 0; mi < 4; ++mi)
        af[mi] = *(const bf16x8*)&As[buf][(mi << 4) + fr][kh * 32 + (fq << 3)];
      #pragma unroll
      for (int ni = 0; ni < 4; ++ni) {
        bf16x8 bv;
        #pragma unroll
        for (int j = 0; j < 8; ++j) bv[j] = (short)bb[kh * 4 + ni][j];
        #pragma unroll
        for (int mi = 0; mi < 4; ++mi)
          acc[mi][ni] = __builtin_amdgcn_mfma_f32_16x16x32_bf16(af[mi], bv, acc[mi][ni], 0, 0, 0);
      }
    }
  };

  const int ksm1 = ksteps - 1;
  // prologue
  loadA0(0);
  loadB(0);
  loadA1(1 < ksm1 ? 1 : ksm1);
  writeA0(0);
  __syncthreads();
  loadA0(2 < ksm1 ? 2 : ksm1);

  for (int t = 0; t + 1 < ksteps; t += 2) {
    // step t: As[0], bb = B(t)
    computeS(0);
    loadB(t + 1);
    writeA1(1);
    __syncthreads();
    loadA1(t + 3 < ksm1 ? t + 3 : ksm1);
    // step t+1: As[1], bb = B(t+1)
    computeS(1);
    loadB(t + 2 < ksm1 ? t + 2 : ksm1);
    writeA0(0);
    __syncthreads();
    loadA0(t + 4 < ksm1 ? t + 4 : ksm1);
  }
  if (ksteps & 1) computeS(0);   // tail: bb = B(ksm1), As[0] = A(ksm1)

  // epilogue: C/D layout col=lane&15, row=(lane>>4)*4+r [m89]
  #pragma unroll
  for (int mi = 0; mi < 4; ++mi) {
    const int row0 = rowBase + (mi << 4) + (fq << 2);
    #pragma unroll
    for (int ni = 0; ni < 4; ++ni) {
      const int col = (wc << 6) + (ni << 4) + fr;
      if (OMODE == 0) {
        if (col < 416) {
          unsigned short* C = (unsigned short*)Cv;
          const float bv = (col < Nreal) ? bias[col] : 0.f;
          #pragma unroll
          for (int r = 0; r < 4; ++r) {
            const int row = row0 + r;
            if (row < M) C[(size_t)row * 416 + col] =
                (col < Nreal) ? f2bf(acc[mi][ni][r] + bv) : (unsigned short)0;
          }
        }
      } else {
        if (col < 70) {
          const float bv = bias[col];
          #pragma unroll
          for (int r = 0; r < 4; ++r) {
            const int row = row0 + r;
            if (row < M) {
              float v = acc[mi][ni][r] + bv;
              if (col < 20) ((float*)Cv)[(size_t)row * 20 + col] = v;
              else          C2[(size_t)row * 50 + (col - 20)] = v;
            }
          }
        }
      }
    }
  }
}

// ---------------- CSR build (both layers fused) ----------------
__global__ void count_deg_all(const int* __restrict__ dst1, int* __restrict__ cnt1, int E1,
                              const int* __restrict__ dst2, int* __restrict__ cnt2, int E2)
{
  int e = blockIdx.x * 256 + threadIdx.x;
  if (e < E1) atomicAdd(&cnt1[dst1[e]], 1);
  else if (e < E1 + E2) atomicAdd(&cnt2[dst2[e - E1]], 1);
}

__device__ void scan_one(const int* __restrict__ cnt, int* __restrict__ indptr, int n,
                         int* sh, int* carrySh)
{
  const int t = threadIdx.x;
  if (t == 0) *carrySh = 0;
  __syncthreads();
  for (int base = 0; base < n; base += 8192) {
    int v[8]; int tsum = 0;
    #pragma unroll
    for (int i = 0; i < 8; ++i) {
      int idx = base + t * 8 + i;
      v[i] = (idx < n) ? cnt[idx] : 0;
      tsum += v[i];
    }
    sh[t] = tsum; __syncthreads();
    for (int off = 1; off < 1024; off <<= 1) {
      int add = (t >= off) ? sh[t - off] : 0;
      __syncthreads();
      sh[t] += add;
      __syncthreads();
    }
    int excl = *carrySh + sh[t] - tsum;
    #pragma unroll
    for (int i = 0; i < 8; ++i) {
      int idx = base + t * 8 + i;
      if (idx < n) indptr[idx] = excl;
      excl += v[i];
    }
    __syncthreads();
    if (t == 1023) *carrySh += sh[1023];
    __syncthreads();
  }
  if (t == 0) indptr[n] = *carrySh;
  __syncthreads();
}

__global__ void scan_indptr2(const int* __restrict__ c1, int* __restrict__ p1, int n1,
                             const int* __restrict__ c2, int* __restrict__ p2, int n2)
{
  __shared__ int sh[1024];
  __shared__ int carrySh;
  scan_one(c1, p1, n1, sh, &carrySh);
  scan_one(c2, p2, n2, sh, &carrySh);
}

__global__ void fill_csr_all(
    const int* __restrict__ src1, const int* __restrict__ dst1, const int* __restrict__ eid1,
    const int* __restrict__ indptr1, int* __restrict__ fill1, int* __restrict__ esrc1, float* __restrict__ ew1, int E1,
    const int* __restrict__ src2, const int* __restrict__ dst2, const int* __restrict__ eid2,
    const int* __restrict__ indptr2, int* __restrict__ fill2, int* __restrict__ esrc2, float* __restrict__ ew2, int E2,
    const float* __restrict__ wall)
{
  int e = blockIdx.x * 256 + threadIdx.x;
  if (e < E1) {
    int d = dst1[e];
    int pos = atomicAdd(&fill1[d], 1);
    int slot = indptr1[d] + pos;
    esrc1[slot] = src1[e];
    ew1[slot] = wall[eid1[e]];
  } else if (e < E1 + E2) {
    int e2 = e - E1;
    int d = dst2[e2];
    int pos = atomicAdd(&fill2[d], 1);
    int slot = indptr2[d] + pos;
    esrc2[slot] = src2[e2];
    ew2[slot] = wall[eid2[e2]];
  }
}

// ---------------- segment mean-aggregate (bf16, stride 416, 8-unrolled) ----------------
__global__ __launch_bounds__(256) void seg_mean_bf(
    const unsigned short* __restrict__ h, const int* __restrict__ indptr,
    const int* __restrict__ esrc, const float* __restrict__ ew,
    unsigned short* __restrict__ out, int nDst)
{
  const int node = blockIdx.x * 4 + (threadIdx.x >> 6);
  if (node >= nDst) return;
  const int lane = threadIdx.x & 63;
  const bool act = lane < 52;                 // 52*8 = 416 dims
  float a[8];
  if (act) {
    ushort8 v = *(const ushort8*)(h + (size_t)node * 416 + lane * 8);
    #pragma unroll
    for (int j = 0; j < 8; ++j) a[j] = bf2f(v[j]);
  } else {
    #pragma unroll
    for (int j = 0; j < 8; ++j) a[j] = 0.f;
  }
  const int e0 = indptr[node], e1 = indptr[node + 1];
  int e = e0;
  for (; e + 8 <= e1; e += 8) {
    const int s0 = esrc[e],     s1 = esrc[e + 1], s2 = esrc[e + 2], s3 = esrc[e + 3];
    const int s4 = esrc[e + 4], s5 = esrc[e + 5], s6 = esrc[e + 6], s7 = esrc[e + 7];
    const float w0 = ew[e],     w1 = ew[e + 1], w2 = ew[e + 2], w3 = ew[e + 3];
    const float w4 = ew[e + 4], w5 = ew[e + 5], w6 = ew[e + 6], w7 = ew[e + 7];
    if (act) {
      ushort8 v0 = *(const ushort8*)(h + (size_t)s0 * 416 + lane * 8);
      ushort8 v1 = *(const ushort8*)(h + (size_t)s1 * 416 + lane * 8);
      ushort8 v2 = *(const ushort8*)(h + (size_t)s2 * 416 + lane * 8);
      ushort8 v3 = *(const ushort8*)(h + (size_t)s3 * 416 + lane * 8);
      ushort8 v4 = *(const ushort8*)(h + (size_t)s4 * 416 + lane * 8);
      ushort8 v5 = *(const ushort8*)(h + (size_t)s5 * 416 + lane * 8);
      ushort8 v6 = *(const ushort8*)(h + (size_t)s6 * 416 + lane * 8);
      ushort8 v7 = *(const ushort8*)(h + (size_t)s7 * 416 + lane * 8);
      #pragma unroll
      for (int j = 0; j < 8; ++j)
        a[j] += ((bf2f(v0[j]) * w0 + bf2f(v1[j]) * w1) + (bf2f(v2[j]) * w2 + bf2f(v3[j]) * w3))
              + ((bf2f(v4[j]) * w4 + bf2f(v5[j]) * w5) + (bf2f(v6[j]) * w6 + bf2f(v7[j]) * w7));
    }
  }
  for (; e < e1; ++e) {
    const int s = esrc[e];
    const float w = ew[e];
    if (act) {
      ushort8 v = *(const ushort8*)(h + (size_t)s * 416 + lane * 8);
      #pragma unroll
      for (int j = 0; j < 8; ++j) a[j] += bf2f(v[j]) * w;
    }
  }
  const float inv = 1.f / ((float)(e1 - e0) + 1.f);
  if (act) {
    ushort8 o;
    #pragma unroll
    for (int j = 0; j < 8; ++j) o[j] = f2bf(a[j] * inv);
    *(ushort8*)(out + (size_t)node * 416 + lane * 8) = o;
  }
}

// ---------------- batchnorm stats + fused finalize/domain head ----------------
__global__ void bn_stats(const float* __restrict__ d, float* __restrict__ stats, int rows) {
  int lane = threadIdx.x & 63;
  int wid = (blockIdx.x * blockDim.x + threadIdx.x) >> 6;
  int nw = (gridDim.x * blockDim.x) >> 6;
  if (lane >= 50) return;
  float s = 0.f, s2 = 0.f;
  for (int r = wid; r < rows; r += nw) {
    float v = d[r * 50 + lane];
    s += v; s2 += v * v;
  }
  atomicAdd(&stats[lane], s);
  atomicAdd(&stats[50 + lane], s2);
}

__global__ void domain_head2(const float* __restrict__ d, const float* __restrict__ stats,
                             const float* __restrict__ gamma, const float* __restrict__ beta,
                             const float* __restrict__ Wd2, const float* __restrict__ bd2,
                             float* __restrict__ out, int rows)
{
  __shared__ float ss[100];
  const int t = threadIdx.x;
  if (t < 50) {
    float mu = stats[t] / rows;
    float var = stats[50 + t] / rows - mu * mu;
    float inv = rsqrtf(var + 1e-5f);
    float sc = gamma[t] * inv;
    ss[t] = sc;
    ss[50 + t] = beta[t] - mu * sc;
  }
  __syncthreads();
  int r = blockIdx.x * 256 + t;
  if (r >= rows) return;
  float o0 = bd2[0], o1 = bd2[1];
  const float* dr = d + (size_t)r * 50;
  #pragma unroll 10
  for (int c = 0; c < 50; ++c) {
    float v = dr[c] * ss[c] + ss[50 + c];
    v = fmaxf(v, 0.f);
    o0 += v * Wd2[c];
    o1 += v * Wd2[50 + c];
  }
  out[r * 2]     = o0;
  out[r * 2 + 1] = o1;
}

// ---------------- launch ----------------
extern "C" void kernel_launch(void* const* d_in, const int* in_sizes, int n_in,
                              void* d_out, int out_size, void* d_ws, size_t ws_size,
                              hipStream_t stream)
{
  const float* x    = (const float*)d_in[0];
  const float* wall = (const float*)d_in[1];
  const float* Wsh  = (const float*)d_in[2];
  const float* bsh  = (const float*)d_in[3];
  const float* Whu  = (const float*)d_in[4];
  const float* bhu  = (const float*)d_in[5];
  const float* Wmo  = (const float*)d_in[6];
  const float* bmo  = (const float*)d_in[7];
  const float* Wn1  = (const float*)d_in[8];
  const float* bn1  = (const float*)d_in[9];
  const float* Wn2  = (const float*)d_in[10];
  const float* bn2  = (const float*)d_in[11];
  const float* Wlin = (const float*)d_in[12];
  const float* blin = (const float*)d_in[13];
  const float* Wd1  = (const float*)d_in[14];
  const float* bd1  = (const float*)d_in[15];
  const float* gamma= (const float*)d_in[16];
  const float* beta = (const float*)d_in[17];
  const float* Wd2  = (const float*)d_in[18];
  const float* bd2  = (const float*)d_in[19];
  const int* src1 = (const int*)d_in[20];
  const int* dst1 = (const int*)d_in[21];
  const int* eid1 = (const int*)d_in[22];
  const int* src2 = (const int*)d_in[23];
  const int* dst2 = (const int*)d_in[24];
  const int* eid2 = (const int*)d_in[25];

  char* ws = (char*)d_ws;
  unsigned short* h    = (unsigned short*)(ws);                    // [60000][416] bf16
  unsigned short* hn1  = (unsigned short*)(ws + 49920000ULL);      // [30000][416]
  unsigned short* h1   = (unsigned short*)(ws + 74880000ULL);      // [30000][416]
  unsigned short* hn2  = (unsigned short*)(ws + 99840000ULL);      // [15000][416]
  unsigned short* h2   = (unsigned short*)(ws + 112320000ULL);     // [15000][416]
  float* d_raw         = (float*)(ws + 124800000ULL);              // [15000][50] f32
  unsigned short* WCf  = (unsigned short*)(ws + 127800000ULL);     // 64*16384 ushorts
  unsigned short* WN1f = (unsigned short*)(ws + 129897152ULL);     // 14*16384
  unsigned short* WN2f = (unsigned short*)(ws + 130355904ULL);
  unsigned short* WHf  = (unsigned short*)(ws + 130814656ULL);
  float* b3      = (float*)(ws + 131273408ULL);
  float* bhead   = (float*)(ws + 131275456ULL);
  // contiguous zero region: cnt1,fill1,cnt2,fill2,stats
  int*   cnt1    = (int*)(ws + 131277504ULL);
  int*   fill1   = (int*)(ws + 131397504ULL);
  int*   cnt2    = (int*)(ws + 131517504ULL);
  int*   fill2   = (int*)(ws + 131577504ULL);
  float* stats   = (float*)(ws + 131637504ULL);
  int*   indptr1 = (int*)(ws + 131637904ULL);
  int*   esrc1   = (int*)(ws + 131757920ULL);
  float* ew1     = (float*)(ws + 135597920ULL);
  int*   indptr2 = (int*)(ws + 139437920ULL);
  int*   esrc2   = (int*)(ws + 139497952ULL);
  float* ew2     = (float*)(ws + 141417952ULL);

  const int E1 = 960000, E2 = 480000;
  const int N0 = 60000, N1 = 30000, N2 = 15000;

  // weight prep (one kernel) + biases (one kernel) + one memset
  build_all_bfrag<<<(106 * 16384 + 255) / 256, 256, 0, stream>>>(
      Wsh, Whu, Wmo, Wn1, Wn2, Wlin, Wd1, WCf, WN1f, WN2f, WHf);
  build_biases<<<1, 512, 0, stream>>>(bsh, bhu, bmo, blin, bd1, b3, bhead);
  (void)hipMemsetAsync(cnt1, 0, 360400, stream);

  // CSR build (both layers fused)
  count_deg_all<<<(E1 + E2 + 255) / 256, 256, 0, stream>>>(dst1, cnt1, E1, dst2, cnt2, E2);
  scan_indptr2<<<1, 1024, 0, stream>>>(cnt1, indptr1, N1, cnt2, indptr2, N2);
  fill_csr_all<<<(E1 + E2 + 255) / 256, 256, 0, stream>>>(
      src1, dst1, eid1, indptr1, fill1, esrc1, ew1, E1,
      src2, dst2, eid2, indptr2, fill2, esrc2, ew2, E2, wall);

  // stage 1: h = bf16(x @ Wcat.T + b3)  [60000][416]   (BK=64, ksteps=32 even)
  gemmk<0, 0><<<938, 512, 0, stream>>>(x, WCf, b3, h, nullptr, N0, 2000, 2000, 32, 400);

  // GNN layer 1
  seg_mean_bf<<<N1 / 4, 256, 0, stream>>>(h, indptr1, esrc1, ew1, hn1, N1);
  gemmk<1, 0><<<469, 512, 0, stream>>>(hn1, WN1f, bn1, h1, nullptr, N1, 416, 416, 7, 400);

  // GNN layer 2
  seg_mean_bf<<<N2 / 4, 256, 0, stream>>>(h1, indptr2, esrc2, ew2, hn2, N2);
  gemmk<1, 0><<<235, 512, 0, stream>>>(hn2, WN2f, bn2, h2, nullptr, N2, 416, 416, 7, 400);

  // fused heads: cols 0..19 -> h_x (d_out), 20..69 -> d_raw
  float* out_hx  = (float*)d_out;            // 15000 x 20
  float* out_dom = (float*)d_out + 300000;   // 15000 x 2
  gemmk<1, 1><<<235, 512, 0, stream>>>(h2, WHf, bhead, out_hx, d_raw, N2, 416, 416, 7, 70);

  bn_stats<<<128, 256, 0, stream>>>(d_raw, stats, N2);
  domain_head2<<<(N2 + 255) / 256, 256, 0, stream>>>(d_raw, stats, gamma, beta, Wd2, bd2, out_dom, N2);
}

// Round 9
// 709.172 us; speedup vs baseline: 6.8509x; 1.0432x over previous
//
#include <hip/hip_runtime.h>
#include <stdint.h>
#include <stddef.h>

typedef short bf16x8 __attribute__((ext_vector_type(8)));
typedef unsigned short ushort8 __attribute__((ext_vector_type(8)));
typedef float f32x4 __attribute__((ext_vector_type(4)));

__device__ __forceinline__ unsigned short f2bf(float f) {
  union { float f; unsigned int u; } v; v.f = f;
  unsigned int r = v.u + 0x7FFFu + ((v.u >> 16) & 1u);  // RNE
  return (unsigned short)(r >> 16);
}
__device__ __forceinline__ float bf2f(unsigned short u) {
  union { unsigned int u; float f; } v; v.u = ((unsigned int)u) << 16; return v.f;
}

// ---------------- unified B fragment builder ----------------
// 32-k-step layout: idx = ((t32*32 + g)*64 + lane)*8 + e
//   col = g*16 + (lane&15); k = t32*32 + (lane>>4)*8 + e
__global__ void build_all_bfrag(
    const float* __restrict__ Wsh, const float* __restrict__ Whu, const float* __restrict__ Wmo,
    const float* __restrict__ Wn1, const float* __restrict__ Wn2,
    const float* __restrict__ Wlin, const float* __restrict__ Wd1,
    unsigned short* __restrict__ WCf, unsigned short* __restrict__ WN1f,
    unsigned short* __restrict__ WN2f, unsigned short* __restrict__ WHf)
{
  const int s0 = 64 * 16384, s1 = s0 + 14 * 16384, s2 = s1 + 14 * 16384, s3 = s2 + 14 * 16384;
  int idx = blockIdx.x * 256 + threadIdx.x;
  if (idx >= s3) return;
  int mode, rel;
  unsigned short* out;
  if (idx < s0)      { mode = 0; rel = idx;      out = WCf;  }
  else if (idx < s1) { mode = 1; rel = idx - s0; out = WN1f; }
  else if (idx < s2) { mode = 3; rel = idx - s1; out = WN2f; }
  else               { mode = 2; rel = idx - s2; out = WHf;  }
  int t = rel >> 14;
  int rem = rel & 16383;
  int e = rem & 7;
  int chunk = rem >> 3;
  int lane = chunk & 63;
  int g = chunk >> 6;
  int col = g * 16 + (lane & 15);
  int k = t * 32 + ((lane >> 4) << 3) + e;
  float v = 0.f;
  if (mode == 0) {
    if (col < 400 && k < 2000) {
      if (k < 1000)      v = Wsh[col * 1000 + k];
      else if (k < 1500) v = Whu[col * 500 + (k - 1000)];
      else               v = Wmo[col * 500 + (k - 1500)];
    }
  } else if (mode == 1) {
    if (col < 400 && k < 400) v = Wn1[col * 400 + k];
  } else if (mode == 3) {
    if (col < 400 && k < 400) v = Wn2[col * 400 + k];
  } else {
    if (k < 400) {
      if (col < 20)      v = Wlin[col * 400 + k];
      else if (col < 70) v = Wd1[(col - 20) * 400 + k];
    }
  }
  out[rel] = f2bf(v);
}

__global__ void build_biases(const float* __restrict__ a, const float* __restrict__ b,
                             const float* __restrict__ c, const float* __restrict__ blin,
                             const float* __restrict__ bd1, float* __restrict__ b3,
                             float* __restrict__ bhead)
{
  int t = threadIdx.x;
  if (t < 416) b3[t] = (t < 400) ? (a[t] + b[t] + c[t]) : 0.f;
  if (t < 512) bhead[t] = (t < 20) ? blin[t] : ((t < 70) ? bd1[t - 20] : 0.f);
}

// ---------------- stage-1 MFMA GEMM: 64x512 block, 512 thr = 8 waves, BK=64 ----------------
__global__ __launch_bounds__(512) void gemm_stage1(
    const float* __restrict__ Af, const unsigned short* __restrict__ Bf,
    const float* __restrict__ bias, unsigned short* __restrict__ C,
    int M, int Kreal, int ksteps)
{
  __shared__ unsigned short As[2][64][72];
  const int tid = threadIdx.x;
  const int lane = tid & 63;
  const int wc = tid >> 6;
  const int rowBase = blockIdx.x * 64;
  const int sRow = tid >> 3;
  const int sC = (tid & 7) << 3;
  const int aRow = rowBase + sRow;
  const bool aOK = aRow < M;
  const int fr = lane & 15;
  const int fq = lane >> 4;

  const unsigned short* bWave = Bf + ((size_t)(wc * 4) * 64 + lane) * 8;

  f32x4 acc[4][4] = {};
  f32x4 a0lo, a0hi, a1lo, a1hi;
  ushort8 bb[16];

  auto loadB = [&](int t) {
    const unsigned short* bp0 = bWave + (size_t)(2 * t) * 16384;
    const unsigned short* bp1 = bWave + (size_t)(2 * t + 1) * 16384;
    #pragma unroll
    for (int ni = 0; ni < 4; ++ni) bb[ni] = *(const ushort8*)(bp0 + ni * 512);
    #pragma unroll
    for (int ni = 0; ni < 4; ++ni) bb[4 + ni] = *(const ushort8*)(bp1 + ni * 512);
  };
  auto loadA0 = [&](int t) {
    const int k0 = t * 64 + sC;
    if (aOK && (k0 + 4) <= Kreal) a0lo = *(const f32x4*)(Af + (size_t)aRow * Kreal + k0);
    else { a0lo[0]=0.f; a0lo[1]=0.f; a0lo[2]=0.f; a0lo[3]=0.f; }
    if (aOK && (k0 + 8) <= Kreal) a0hi = *(const f32x4*)(Af + (size_t)aRow * Kreal + k0 + 4);
    else { a0hi[0]=0.f; a0hi[1]=0.f; a0hi[2]=0.f; a0hi[3]=0.f; }
  };
  auto loadA1 = [&](int t) {
    const int k0 = t * 64 + sC;
    if (aOK && (k0 + 4) <= Kreal) a1lo = *(const f32x4*)(Af + (size_t)aRow * Kreal + k0);
    else { a1lo[0]=0.f; a1lo[1]=0.f; a1lo[2]=0.f; a1lo[3]=0.f; }
    if (aOK && (k0 + 8) <= Kreal) a1hi = *(const f32x4*)(Af + (size_t)aRow * Kreal + k0 + 4);
    else { a1hi[0]=0.f; a1hi[1]=0.f; a1hi[2]=0.f; a1hi[3]=0.f; }
  };
  auto writeA0 = [&](int buf) {
    ushort8 w;
    w[0]=f2bf(a0lo[0]); w[1]=f2bf(a0lo[1]); w[2]=f2bf(a0lo[2]); w[3]=f2bf(a0lo[3]);
    w[4]=f2bf(a0hi[0]); w[5]=f2bf(a0hi[1]); w[6]=f2bf(a0hi[2]); w[7]=f2bf(a0hi[3]);
    *(ushort8*)&As[buf][sRow][sC] = w;
  };
  auto writeA1 = [&](int buf) {
    ushort8 w;
    w[0]=f2bf(a1lo[0]); w[1]=f2bf(a1lo[1]); w[2]=f2bf(a1lo[2]); w[3]=f2bf(a1lo[3]);
    w[4]=f2bf(a1hi[0]); w[5]=f2bf(a1hi[1]); w[6]=f2bf(a1hi[2]); w[7]=f2bf(a1hi[3]);
    *(ushort8*)&As[buf][sRow][sC] = w;
  };
  auto computeS = [&](int buf) {
    #pragma unroll
    for (int kh = 0; kh < 2; ++kh) {
      bf16x8 af[4];
      #pragma unroll
      for (int mi = 0; mi < 4; ++mi)
        af[mi] = *(const bf16x8*)&As[buf][(mi << 4) + fr][kh * 32 + (fq << 3)];
      #pragma unroll
      for (int ni = 0; ni < 4; ++ni) {
        bf16x8 bv;
        #pragma unroll
        for (int j = 0; j < 8; ++j) bv[j] = (short)bb[kh * 4 + ni][j];
        #pragma unroll
        for (int mi = 0; mi < 4; ++mi)
          acc[mi][ni] = __builtin_amdgcn_mfma_f32_16x16x32_bf16(af[mi], bv, acc[mi][ni], 0, 0, 0);
      }
    }
  };

  const int ksm1 = ksteps - 1;
  loadA0(0);
  loadB(0);
  loadA1(1 < ksm1 ? 1 : ksm1);
  writeA0(0);
  __syncthreads();
  loadA0(2 < ksm1 ? 2 : ksm1);

  for (int t = 0; t + 1 < ksteps; t += 2) {
    computeS(0);
    loadB(t + 1);
    writeA1(1);
    __syncthreads();
    loadA1(t + 3 < ksm1 ? t + 3 : ksm1);
    computeS(1);
    loadB(t + 2 < ksm1 ? t + 2 : ksm1);
    writeA0(0);
    __syncthreads();
    loadA0(t + 4 < ksm1 ? t + 4 : ksm1);
  }
  if (ksteps & 1) computeS(0);

  #pragma unroll
  for (int mi = 0; mi < 4; ++mi) {
    const int row0 = rowBase + (mi << 4) + (fq << 2);
    #pragma unroll
    for (int ni = 0; ni < 4; ++ni) {
      const int col = (wc << 6) + (ni << 4) + fr;
      if (col < 416) {
        const float bv = (col < 400) ? bias[col] : 0.f;
        #pragma unroll
        for (int r = 0; r < 4; ++r) {
          const int row = row0 + r;
          if (row < M) C[(size_t)row * 416 + col] =
              (col < 400) ? f2bf(acc[mi][ni][r] + bv) : (unsigned short)0;
        }
      }
    }
  }
}

// ---------------- fused GNN layer: gather-aggregate -> LDS -> GEMM (-> head) ----------------
// 512 thr = 8 waves. Block = 64 dst nodes. LDS tile T[64][456] bf16 (cols 416..455 zero).
// Phase1: wave wv aggregates nodes wv*8..wv*8+7. Phase2: 64x512 GEMM, A from LDS (no
// barriers in K-loop), B kh-dbuf from global frags. HEAD=1: write h2 back to T, run
// 64x128 head GEMM (cols 0..69 -> outHx/dRaw) instead of storing C globally.
template<int HEAD>
__global__ __launch_bounds__(512) void fused_layer(
    const unsigned short* __restrict__ hsrc, const int* __restrict__ indptr,
    const int* __restrict__ esrc, const float* __restrict__ ew,
    const unsigned short* __restrict__ Bf, const float* __restrict__ bias,
    unsigned short* __restrict__ Cout,
    const unsigned short* __restrict__ BfH, const float* __restrict__ biasH,
    float* __restrict__ outHx, float* __restrict__ dRaw, int nDst)
{
  __shared__ unsigned short T[64][456];
  const int tid = threadIdx.x;
  const int lane = tid & 63;
  const int wv = tid >> 6;            // 0..7
  const int rowBase = blockIdx.x * 64;
  const int fr = lane & 15;
  const int fq = lane >> 4;

  // ---- Phase 1: aggregate 8 nodes per wave into T ----
  for (int i = 0; i < 8; ++i) {
    const int row = wv * 8 + i;
    const int node = rowBase + row;
    if (lane < 52) {
      float a[8];
      if (node < nDst) {
        ushort8 v = *(const ushort8*)(hsrc + (size_t)node * 416 + lane * 8);
        #pragma unroll
        for (int j = 0; j < 8; ++j) a[j] = bf2f(v[j]);
        const int e0 = indptr[node], e1 = indptr[node + 1];
        int e = e0;
        for (; e + 4 <= e1; e += 4) {
          const int s0 = esrc[e], s1 = esrc[e+1], s2 = esrc[e+2], s3 = esrc[e+3];
          const float w0 = ew[e], w1 = ew[e+1], w2 = ew[e+2], w3 = ew[e+3];
          ushort8 v0 = *(const ushort8*)(hsrc + (size_t)s0 * 416 + lane * 8);
          ushort8 v1 = *(const ushort8*)(hsrc + (size_t)s1 * 416 + lane * 8);
          ushort8 v2 = *(const ushort8*)(hsrc + (size_t)s2 * 416 + lane * 8);
          ushort8 v3 = *(const ushort8*)(hsrc + (size_t)s3 * 416 + lane * 8);
          #pragma unroll
          for (int j = 0; j < 8; ++j)
            a[j] += (bf2f(v0[j]) * w0 + bf2f(v1[j]) * w1) + (bf2f(v2[j]) * w2 + bf2f(v3[j]) * w3);
        }
        for (; e < e1; ++e) {
          const int s = esrc[e];
          const float w = ew[e];
          ushort8 v = *(const ushort8*)(hsrc + (size_t)s * 416 + lane * 8);
          #pragma unroll
          for (int j = 0; j < 8; ++j) a[j] += bf2f(v[j]) * w;
        }
        const float inv = 1.f / ((float)(e1 - e0) + 1.f);
        ushort8 o;
        #pragma unroll
        for (int j = 0; j < 8; ++j) o[j] = f2bf(a[j] * inv);
        *(ushort8*)&T[row][lane * 8] = o;
      } else {
        ushort8 o;
        #pragma unroll
        for (int j = 0; j < 8; ++j) o[j] = 0;
        *(ushort8*)&T[row][lane * 8] = o;
      }
    } else if (lane < 57) {           // zero pad cols 416..455
      ushort8 o;
      #pragma unroll
      for (int j = 0; j < 8; ++j) o[j] = 0;
      *(ushort8*)&T[row][416 + (lane - 52) * 8] = o;
    }
  }
  __syncthreads();

  // ---- Phase 2: 64x512 GEMM, A resident in T, B kh-dbuf from global ----
  const unsigned short* bWave = Bf + ((size_t)(wv * 4) * 64 + lane) * 8;
  f32x4 acc[4][4] = {};
  ushort8 bbA[4], bbB[4];

  auto loadBA = [&](int kh) {
    const unsigned short* bp = bWave + (size_t)kh * 16384;
    #pragma unroll
    for (int ni = 0; ni < 4; ++ni) bbA[ni] = *(const ushort8*)(bp + ni * 512);
  };
  auto loadBB = [&](int kh) {
    const unsigned short* bp = bWave + (size_t)kh * 16384;
    #pragma unroll
    for (int ni = 0; ni < 4; ++ni) bbB[ni] = *(const ushort8*)(bp + ni * 512);
  };
  auto computeA2 = [&](int kh) {
    bf16x8 af[4];
    #pragma unroll
    for (int mi = 0; mi < 4; ++mi)
      af[mi] = *(const bf16x8*)&T[(mi << 4) + fr][kh * 32 + (fq << 3)];
    #pragma unroll
    for (int ni = 0; ni < 4; ++ni) {
      bf16x8 bv;
      #pragma unroll
      for (int j = 0; j < 8; ++j) bv[j] = (short)bbA[ni][j];
      #pragma unroll
      for (int mi = 0; mi < 4; ++mi)
        acc[mi][ni] = __builtin_amdgcn_mfma_f32_16x16x32_bf16(af[mi], bv, acc[mi][ni], 0, 0, 0);
    }
  };
  auto computeB2 = [&](int kh) {
    bf16x8 af[4];
    #pragma unroll
    for (int mi = 0; mi < 4; ++mi)
      af[mi] = *(const bf16x8*)&T[(mi << 4) + fr][kh * 32 + (fq << 3)];
    #pragma unroll
    for (int ni = 0; ni < 4; ++ni) {
      bf16x8 bv;
      #pragma unroll
      for (int j = 0; j < 8; ++j) bv[j] = (short)bbB[ni][j];
      #pragma unroll
      for (int mi = 0; mi < 4; ++mi)
        acc[mi][ni] = __builtin_amdgcn_mfma_f32_16x16x32_bf16(af[mi], bv, acc[mi][ni], 0, 0, 0);
    }
  };

  loadBA(0);
  loadBB(1);
  for (int kh = 0; kh + 1 < 14; kh += 2) {
    computeA2(kh);
    loadBA(kh + 2 < 13 ? kh + 2 : 13);
    computeB2(kh + 1);
    loadBB(kh + 3 < 13 ? kh + 3 : 13);
  }

  if (HEAD == 0) {
    // store C = bf16(acc + bias) to global [nDst][416]
    #pragma unroll
    for (int mi = 0; mi < 4; ++mi) {
      const int row0 = rowBase + (mi << 4) + (fq << 2);
      #pragma unroll
      for (int ni = 0; ni < 4; ++ni) {
        const int col = (wv << 6) + (ni << 4) + fr;
        if (col < 416) {
          const float bv = (col < 400) ? bias[col] : 0.f;
          #pragma unroll
          for (int r = 0; r < 4; ++r) {
            const int row = row0 + r;
            if (row < nDst) Cout[(size_t)row * 416 + col] =
                (col < 400) ? f2bf(acc[mi][ni][r] + bv) : (unsigned short)0;
          }
        }
      }
    }
  } else {
    // write h2 = bf16(acc + bias) back into T, then head GEMM
    __syncthreads();   // all phase-2 reads of T complete
    #pragma unroll
    for (int mi = 0; mi < 4; ++mi) {
      const int lrow0 = (mi << 4) + (fq << 2);
      #pragma unroll
      for (int ni = 0; ni < 4; ++ni) {
        const int col = (wv << 6) + (ni << 4) + fr;
        if (col < 456) {
          const float bv = (col < 400) ? bias[col] : 0.f;
          #pragma unroll
          for (int r = 0; r < 4; ++r)
            T[lrow0 + r][col] = (col < 400) ? f2bf(acc[mi][ni][r] + bv) : (unsigned short)0;
        }
      }
    }
    __syncthreads();
    // head: 64x128, wave wv covers cols wv*16..wv*16+15 (only cols<70 real)
    const unsigned short* bhWave = BfH + ((size_t)wv * 64 + lane) * 8;
    f32x4 acc2[4] = {};
    ushort8 bhA, bhB;
    auto loadHA = [&](int kh) { bhA = *(const ushort8*)(bhWave + (size_t)kh * 16384); };
    auto loadHB = [&](int kh) { bhB = *(const ushort8*)(bhWave + (size_t)kh * 16384); };
    auto computeHA = [&](int kh) {
      bf16x8 bv;
      #pragma unroll
      for (int j = 0; j < 8; ++j) bv[j] = (short)bhA[j];
      #pragma unroll
      for (int mi = 0; mi < 4; ++mi) {
        bf16x8 af = *(const bf16x8*)&T[(mi << 4) + fr][kh * 32 + (fq << 3)];
        acc2[mi] = __builtin_amdgcn_mfma_f32_16x16x32_bf16(af, bv, acc2[mi], 0, 0, 0);
      }
    };
    auto computeHB = [&](int kh) {
      bf16x8 bv;
      #pragma unroll
      for (int j = 0; j < 8; ++j) bv[j] = (short)bhB[j];
      #pragma unroll
      for (int mi = 0; mi < 4; ++mi) {
        bf16x8 af = *(const bf16x8*)&T[(mi << 4) + fr][kh * 32 + (fq << 3)];
        acc2[mi] = __builtin_amdgcn_mfma_f32_16x16x32_bf16(af, bv, acc2[mi], 0, 0, 0);
      }
    };
    loadHA(0);
    loadHB(1);
    for (int kh = 0; kh + 1 < 14; kh += 2) {
      computeHA(kh);
      loadHA(kh + 2 < 13 ? kh + 2 : 13);
      computeHB(kh + 1);
      loadHB(kh + 3 < 13 ? kh + 3 : 13);
    }
    const int col = (wv << 4) + fr;
    if (col < 70) {
      const float bv = biasH[col];
      #pragma unroll
      for (int mi = 0; mi < 4; ++mi) {
        const int row0 = rowBase + (mi << 4) + (fq << 2);
        #pragma unroll
        for (int r = 0; r < 4; ++r) {
          const int row = row0 + r;
          if (row < nDst) {
            float v = acc2[mi][r] + bv;
            if (col < 20) outHx[(size_t)row * 20 + col] = v;
            else          dRaw[(size_t)row * 50 + (col - 20)] = v;
          }
        }
      }
    }
  }
}

// ---------------- CSR build (both layers fused) ----------------
__global__ void count_deg_all(const int* __restrict__ dst1, int* __restrict__ cnt1, int E1,
                              const int* __restrict__ dst2, int* __restrict__ cnt2, int E2)
{
  int e = blockIdx.x * 256 + threadIdx.x;
  if (e < E1) atomicAdd(&cnt1[dst1[e]], 1);
  else if (e < E1 + E2) atomicAdd(&cnt2[dst2[e - E1]], 1);
}

__device__ void scan_one(const int* __restrict__ cnt, int* __restrict__ indptr, int n,
                         int* sh, int* carrySh)
{
  const int t = threadIdx.x;
  if (t == 0) *carrySh = 0;
  __syncthreads();
  for (int base = 0; base < n; base += 8192) {
    int v[8]; int tsum = 0;
    #pragma unroll
    for (int i = 0; i < 8; ++i) {
      int idx = base + t * 8 + i;
      v[i] = (idx < n) ? cnt[idx] : 0;
      tsum += v[i];
    }
    sh[t] = tsum; __syncthreads();
    for (int off = 1; off < 1024; off <<= 1) {
      int add = (t >= off) ? sh[t - off] : 0;
      __syncthreads();
      sh[t] += add;
      __syncthreads();
    }
    int excl = *carrySh + sh[t] - tsum;
    #pragma unroll
    for (int i = 0; i < 8; ++i) {
      int idx = base + t * 8 + i;
      if (idx < n) indptr[idx] = excl;
      excl += v[i];
    }
    __syncthreads();
    if (t == 1023) *carrySh += sh[1023];
    __syncthreads();
  }
  if (t == 0) indptr[n] = *carrySh;
  __syncthreads();
}

__global__ void scan_indptr2(const int* __restrict__ c1, int* __restrict__ p1, int n1,
                             const int* __restrict__ c2, int* __restrict__ p2, int n2)
{
  __shared__ int sh[1024];
  __shared__ int carrySh;
  scan_one(c1, p1, n1, sh, &carrySh);
  scan_one(c2, p2, n2, sh, &carrySh);
}

__global__ void fill_csr_all(
    const int* __restrict__ src1, const int* __restrict__ dst1, const int* __restrict__ eid1,
    const int* __restrict__ indptr1, int* __restrict__ fill1, int* __restrict__ esrc1, float* __restrict__ ew1, int E1,
    const int* __restrict__ src2, const int* __restrict__ dst2, const int* __restrict__ eid2,
    const int* __restrict__ indptr2, int* __restrict__ fill2, int* __restrict__ esrc2, float* __restrict__ ew2, int E2,
    const float* __restrict__ wall)
{
  int e = blockIdx.x * 256 + threadIdx.x;
  if (e < E1) {
    int d = dst1[e];
    int pos = atomicAdd(&fill1[d], 1);
    int slot = indptr1[d] + pos;
    esrc1[slot] = src1[e];
    ew1[slot] = wall[eid1[e]];
  } else if (e < E1 + E2) {
    int e2 = e - E1;
    int d = dst2[e2];
    int pos = atomicAdd(&fill2[d], 1);
    int slot = indptr2[d] + pos;
    esrc2[slot] = src2[e2];
    ew2[slot] = wall[eid2[e2]];
  }
}

// ---------------- batchnorm stats + fused finalize/domain head ----------------
__global__ void bn_stats(const float* __restrict__ d, float* __restrict__ stats, int rows) {
  int lane = threadIdx.x & 63;
  int wid = (blockIdx.x * blockDim.x + threadIdx.x) >> 6;
  int nw = (gridDim.x * blockDim.x) >> 6;
  if (lane >= 50) return;
  float s = 0.f, s2 = 0.f;
  for (int r = wid; r < rows; r += nw) {
    float v = d[r * 50 + lane];
    s += v; s2 += v * v;
  }
  atomicAdd(&stats[lane], s);
  atomicAdd(&stats[50 + lane], s2);
}

__global__ void domain_head2(const float* __restrict__ d, const float* __restrict__ stats,
                             const float* __restrict__ gamma, const float* __restrict__ beta,
                             const float* __restrict__ Wd2, const float* __restrict__ bd2,
                             float* __restrict__ out, int rows)
{
  __shared__ float ss[100];
  const int t = threadIdx.x;
  if (t < 50) {
    float mu = stats[t] / rows;
    float var = stats[50 + t] / rows - mu * mu;
    float inv = rsqrtf(var + 1e-5f);
    float sc = gamma[t] * inv;
    ss[t] = sc;
    ss[50 + t] = beta[t] - mu * sc;
  }
  __syncthreads();
  int r = blockIdx.x * 256 + t;
  if (r >= rows) return;
  float o0 = bd2[0], o1 = bd2[1];
  const float* dr = d + (size_t)r * 50;
  #pragma unroll 10
  for (int c = 0; c < 50; ++c) {
    float v = dr[c] * ss[c] + ss[50 + c];
    v = fmaxf(v, 0.f);
    o0 += v * Wd2[c];
    o1 += v * Wd2[50 + c];
  }
  out[r * 2]     = o0;
  out[r * 2 + 1] = o1;
}

// ---------------- launch ----------------
extern "C" void kernel_launch(void* const* d_in, const int* in_sizes, int n_in,
                              void* d_out, int out_size, void* d_ws, size_t ws_size,
                              hipStream_t stream)
{
  const float* x    = (const float*)d_in[0];
  const float* wall = (const float*)d_in[1];
  const float* Wsh  = (const float*)d_in[2];
  const float* bsh  = (const float*)d_in[3];
  const float* Whu  = (const float*)d_in[4];
  const float* bhu  = (const float*)d_in[5];
  const float* Wmo  = (const float*)d_in[6];
  const float* bmo  = (const float*)d_in[7];
  const float* Wn1  = (const float*)d_in[8];
  const float* bn1  = (const float*)d_in[9];
  const float* Wn2  = (const float*)d_in[10];
  const float* bn2  = (const float*)d_in[11];
  const float* Wlin = (const float*)d_in[12];
  const float* blin = (const float*)d_in[13];
  const float* Wd1  = (const float*)d_in[14];
  const float* bd1  = (const float*)d_in[15];
  const float* gamma= (const float*)d_in[16];
  const float* beta = (const float*)d_in[17];
  const float* Wd2  = (const float*)d_in[18];
  const float* bd2  = (const float*)d_in[19];
  const int* src1 = (const int*)d_in[20];
  const int* dst1 = (const int*)d_in[21];
  const int* eid1 = (const int*)d_in[22];
  const int* src2 = (const int*)d_in[23];
  const int* dst2 = (const int*)d_in[24];
  const int* eid2 = (const int*)d_in[25];

  char* ws = (char*)d_ws;
  unsigned short* h    = (unsigned short*)(ws);                    // [60000][416] bf16
  unsigned short* h1   = (unsigned short*)(ws + 49920000ULL);      // [30000][416]
  float* d_raw         = (float*)(ws + 74880000ULL);               // [15000][50] f32
  unsigned short* WCf  = (unsigned short*)(ws + 77880000ULL);      // 64*16384 ushorts
  unsigned short* WN1f = (unsigned short*)(ws + 79977152ULL);      // 14*16384
  unsigned short* WN2f = (unsigned short*)(ws + 80435904ULL);
  unsigned short* WHf  = (unsigned short*)(ws + 80894656ULL);
  float* b3      = (float*)(ws + 81353408ULL);
  float* bhead   = (float*)(ws + 81355456ULL);
  // contiguous zero region: cnt1,fill1,cnt2,fill2,stats
  int*   cnt1    = (int*)(ws + 81357504ULL);
  int*   fill1   = (int*)(ws + 81477504ULL);
  int*   cnt2    = (int*)(ws + 81597504ULL);
  int*   fill2   = (int*)(ws + 81657504ULL);
  float* stats   = (float*)(ws + 81717504ULL);
  int*   indptr1 = (int*)(ws + 81717904ULL);
  int*   esrc1   = (int*)(ws + 81837920ULL);
  float* ew1     = (float*)(ws + 85677920ULL);
  int*   indptr2 = (int*)(ws + 89517920ULL);
  int*   esrc2   = (int*)(ws + 89577952ULL);
  float* ew2     = (float*)(ws + 91497952ULL);

  const int E1 = 960000, E2 = 480000;
  const int N0 = 60000, N1 = 30000, N2 = 15000;

  build_all_bfrag<<<(106 * 16384 + 255) / 256, 256, 0, stream>>>(
      Wsh, Whu, Wmo, Wn1, Wn2, Wlin, Wd1, WCf, WN1f, WN2f, WHf);
  build_biases<<<1, 512, 0, stream>>>(bsh, bhu, bmo, blin, bd1, b3, bhead);
  (void)hipMemsetAsync(cnt1, 0, 360400, stream);

  count_deg_all<<<(E1 + E2 + 255) / 256, 256, 0, stream>>>(dst1, cnt1, E1, dst2, cnt2, E2);
  scan_indptr2<<<1, 1024, 0, stream>>>(cnt1, indptr1, N1, cnt2, indptr2, N2);
  fill_csr_all<<<(E1 + E2 + 255) / 256, 256, 0, stream>>>(
      src1, dst1, eid1, indptr1, fill1, esrc1, ew1, E1,
      src2, dst2, eid2, indptr2, fill2, esrc2, ew2, E2, wall);

  // stage 1: h = bf16(x @ Wcat.T + b3)
  gemm_stage1<<<938, 512, 0, stream>>>(x, WCf, b3, h, N0, 2000, 32);

  float* out_hx  = (float*)d_out;            // 15000 x 20
  float* out_dom = (float*)d_out + 300000;   // 15000 x 2

  // layer 1: gather(h) -> GEMM(WN1) -> h1
  fused_layer<0><<<(N1 + 63) / 64, 512, 0, stream>>>(
      h, indptr1, esrc1, ew1, WN1f, bn1, h1, nullptr, nullptr, nullptr, nullptr, N1);

  // layer 2 + head: gather(h1) -> GEMM(WN2) -> h2(LDS) -> head GEMM -> out_hx, d_raw
  fused_layer<1><<<(N2 + 63) / 64, 512, 0, stream>>>(
      h1, indptr2, esrc2, ew2, WN2f, bn2, nullptr, WHf, bhead, out_hx, d_raw, N2);

  bn_stats<<<128, 256, 0, stream>>>(d_raw, stats, N2);
  domain_head2<<<(N2 + 255) / 256, 256, 0, stream>>>(d_raw, stats, gamma, beta, Wd2, bd2, out_dom, N2);
}

// Round 10
// 625.566 us; speedup vs baseline: 7.7665x; 1.1336x over previous
//
#include <hip/hip_runtime.h>
#include <stdint.h>
#include <stddef.h>

typedef short bf16x8 __attribute__((ext_vector_type(8)));
typedef unsigned short ushort8 __attribute__((ext_vector_type(8)));
typedef float f32x4 __attribute__((ext_vector_type(4)));

__device__ __forceinline__ unsigned short f2bf(float f) {
  union { float f; unsigned int u; } v; v.f = f;
  unsigned int r = v.u + 0x7FFFu + ((v.u >> 16) & 1u);  // RNE
  return (unsigned short)(r >> 16);
}
__device__ __forceinline__ float bf2f(unsigned short u) {
  union { unsigned int u; float f; } v; v.u = ((unsigned int)u) << 16; return v.f;
}

// ---------------- merged prep: B-fragments + degree count + biases ----------------
// frag layout: rel = ((t32*32 + g)*64 + lane)*8 + e ; col = g*16+(lane&15); k = t32*32+(lane>>4)*8+e
__global__ void prep_all(
    const float* __restrict__ Wsh, const float* __restrict__ Whu, const float* __restrict__ Wmo,
    const float* __restrict__ Wn1, const float* __restrict__ Wn2,
    const float* __restrict__ Wlin, const float* __restrict__ Wd1,
    unsigned short* __restrict__ WCf, unsigned short* __restrict__ WN1f,
    unsigned short* __restrict__ WN2f, unsigned short* __restrict__ WHf,
    const float* __restrict__ bsh, const float* __restrict__ bhu, const float* __restrict__ bmo,
    const float* __restrict__ blin, const float* __restrict__ bd1,
    float* __restrict__ b3, float* __restrict__ bhead,
    const int* __restrict__ dst1, int* __restrict__ cnt1, int E1,
    const int* __restrict__ dst2, int* __restrict__ cnt2, int E2)
{
  const int NB_FRAG = 6784;   // 106*16384/256
  const int NB_CNT  = 5625;   // (E1+E2)/256
  const int bid = blockIdx.x;
  const int tid = threadIdx.x;
  if (bid < NB_FRAG) {
    const int s0 = 64 * 16384, s1 = s0 + 14 * 16384, s2 = s1 + 14 * 16384;
    int idx = bid * 256 + tid;
    int mode, rel;
    unsigned short* out;
    if (idx < s0)      { mode = 0; rel = idx;      out = WCf;  }
    else if (idx < s1) { mode = 1; rel = idx - s0; out = WN1f; }
    else if (idx < s2) { mode = 3; rel = idx - s1; out = WN2f; }
    else               { mode = 2; rel = idx - s2; out = WHf;  }
    int t = rel >> 14;
    int rem = rel & 16383;
    int e = rem & 7;
    int chunk = rem >> 3;
    int lane = chunk & 63;
    int g = chunk >> 6;
    int col = g * 16 + (lane & 15);
    int k = t * 32 + ((lane >> 4) << 3) + e;
    float v = 0.f;
    if (mode == 0) {
      if (col < 400 && k < 2000) {
        if (k < 1000)      v = Wsh[col * 1000 + k];
        else if (k < 1500) v = Whu[col * 500 + (k - 1000)];
        else               v = Wmo[col * 500 + (k - 1500)];
      }
    } else if (mode == 1) {
      if (col < 400 && k < 400) v = Wn1[col * 400 + k];
    } else if (mode == 3) {
      if (col < 400 && k < 400) v = Wn2[col * 400 + k];
    } else {
      if (k < 400) {
        if (col < 20)      v = Wlin[col * 400 + k];
        else if (col < 70) v = Wd1[(col - 20) * 400 + k];
      }
    }
    out[rel] = f2bf(v);
  } else if (bid < NB_FRAG + NB_CNT) {
    int e = (bid - NB_FRAG) * 256 + tid;
    if (e < E1) atomicAdd(&cnt1[dst1[e]], 1);
    else if (e < E1 + E2) atomicAdd(&cnt2[dst2[e - E1]], 1);
  } else {
    for (int t = tid; t < 512; t += 256) {
      if (t < 416) b3[t] = (t < 400) ? (bsh[t] + bhu[t] + bmo[t]) : 0.f;
      bhead[t] = (t < 20) ? blin[t] : ((t < 70) ? bd1[t - 20] : 0.f);
    }
  }
}

// ---------------- 512-thread exclusive scan helper ----------------
__device__ void scan512(const int* __restrict__ cnt, int* __restrict__ indptr, int n,
                        int* sh, int* carrySh)
{
  const int t = threadIdx.x;
  if (t == 0) *carrySh = 0;
  __syncthreads();
  for (int base = 0; base < n; base += 8192) {
    int v[16]; int tsum = 0;
    #pragma unroll
    for (int i = 0; i < 16; ++i) {
      int idx = base + t * 16 + i;
      v[i] = (idx < n) ? cnt[idx] : 0;
      tsum += v[i];
    }
    sh[t] = tsum; __syncthreads();
    for (int off = 1; off < 512; off <<= 1) {
      int add = (t >= off) ? sh[t - off] : 0;
      __syncthreads();
      sh[t] += add;
      __syncthreads();
    }
    int excl = *carrySh + sh[t] - tsum;
    #pragma unroll
    for (int i = 0; i < 16; ++i) {
      int idx = base + t * 16 + i;
      if (idx < n) indptr[idx] = excl;
      excl += v[i];
    }
    __syncthreads();
    if (t == 511) *carrySh += sh[511];
    __syncthreads();
  }
  if (t == 0) indptr[n] = *carrySh;
  __syncthreads();
}

// ---------------- stage-1 GEMM (64x512, 8 waves, BK=64) + embedded CSR scan ----------------
// Blocks 0..937: GEMM. Last block: exclusive scans (independent of GEMM inputs).
__global__ __launch_bounds__(512) void gemm_stage1_scan(
    const float* __restrict__ Af, const unsigned short* __restrict__ Bf,
    const float* __restrict__ bias, unsigned short* __restrict__ C,
    int M, int Kreal, int ksteps,
    const int* __restrict__ cnt1, int* __restrict__ indptr1, int n1,
    const int* __restrict__ cnt2, int* __restrict__ indptr2, int n2)
{
  __shared__ unsigned short As[2][64][72];
  __shared__ int sh[512];
  __shared__ int carrySh;

  if (blockIdx.x == gridDim.x - 1) {
    scan512(cnt1, indptr1, n1, sh, &carrySh);
    scan512(cnt2, indptr2, n2, sh, &carrySh);
    return;
  }

  const int tid = threadIdx.x;
  const int lane = tid & 63;
  const int wc = tid >> 6;
  const int rowBase = blockIdx.x * 64;
  const int sRow = tid >> 3;
  const int sC = (tid & 7) << 3;
  const int aRow = rowBase + sRow;
  const bool aOK = aRow < M;
  const int fr = lane & 15;
  const int fq = lane >> 4;

  const unsigned short* bWave = Bf + ((size_t)(wc * 4) * 64 + lane) * 8;

  f32x4 acc[4][4] = {};
  f32x4 a0lo, a0hi, a1lo, a1hi;
  bf16x8 bb[16];

  auto loadB = [&](int t) {
    const unsigned short* bp0 = bWave + (size_t)(2 * t) * 16384;
    const unsigned short* bp1 = bWave + (size_t)(2 * t + 1) * 16384;
    #pragma unroll
    for (int ni = 0; ni < 4; ++ni) bb[ni] = *(const bf16x8*)(bp0 + ni * 512);
    #pragma unroll
    for (int ni = 0; ni < 4; ++ni) bb[4 + ni] = *(const bf16x8*)(bp1 + ni * 512);
  };
  auto loadA0 = [&](int t) {
    const int k0 = t * 64 + sC;
    if (aOK && (k0 + 4) <= Kreal) a0lo = *(const f32x4*)(Af + (size_t)aRow * Kreal + k0);
    else { a0lo[0]=0.f; a0lo[1]=0.f; a0lo[2]=0.f; a0lo[3]=0.f; }
    if (aOK && (k0 + 8) <= Kreal) a0hi = *(const f32x4*)(Af + (size_t)aRow * Kreal + k0 + 4);
    else { a0hi[0]=0.f; a0hi[1]=0.f; a0hi[2]=0.f; a0hi[3]=0.f; }
  };
  auto loadA1 = [&](int t) {
    const int k0 = t * 64 + sC;
    if (aOK && (k0 + 4) <= Kreal) a1lo = *(const f32x4*)(Af + (size_t)aRow * Kreal + k0);
    else { a1lo[0]=0.f; a1lo[1]=0.f; a1lo[2]=0.f; a1lo[3]=0.f; }
    if (aOK && (k0 + 8) <= Kreal) a1hi = *(const f32x4*)(Af + (size_t)aRow * Kreal + k0 + 4);
    else { a1hi[0]=0.f; a1hi[1]=0.f; a1hi[2]=0.f; a1hi[3]=0.f; }
  };
  auto writeA0 = [&](int buf) {
    ushort8 w;
    w[0]=f2bf(a0lo[0]); w[1]=f2bf(a0lo[1]); w[2]=f2bf(a0lo[2]); w[3]=f2bf(a0lo[3]);
    w[4]=f2bf(a0hi[0]); w[5]=f2bf(a0hi[1]); w[6]=f2bf(a0hi[2]); w[7]=f2bf(a0hi[3]);
    *(ushort8*)&As[buf][sRow][sC] = w;
  };
  auto writeA1 = [&](int buf) {
    ushort8 w;
    w[0]=f2bf(a1lo[0]); w[1]=f2bf(a1lo[1]); w[2]=f2bf(a1lo[2]); w[3]=f2bf(a1lo[3]);
    w[4]=f2bf(a1hi[0]); w[5]=f2bf(a1hi[1]); w[6]=f2bf(a1hi[2]); w[7]=f2bf(a1hi[3]);
    *(ushort8*)&As[buf][sRow][sC] = w;
  };
  auto computeS = [&](int buf) {
    #pragma unroll
    for (int kh = 0; kh < 2; ++kh) {
      bf16x8 af[4];
      #pragma unroll
      for (int mi = 0; mi < 4; ++mi)
        af[mi] = *(const bf16x8*)&As[buf][(mi << 4) + fr][kh * 32 + (fq << 3)];
      #pragma unroll
      for (int ni = 0; ni < 4; ++ni)
        #pragma unroll
        for (int mi = 0; mi < 4; ++mi)
          acc[mi][ni] = __builtin_amdgcn_mfma_f32_16x16x32_bf16(af[mi], bb[kh * 4 + ni], acc[mi][ni], 0, 0, 0);
    }
  };

  const int ksm1 = ksteps - 1;
  loadA0(0);
  loadB(0);
  loadA1(1 < ksm1 ? 1 : ksm1);
  writeA0(0);
  __syncthreads();
  loadA0(2 < ksm1 ? 2 : ksm1);

  for (int t = 0; t + 1 < ksteps; t += 2) {
    computeS(0);
    loadB(t + 1);
    writeA1(1);
    __syncthreads();
    loadA1(t + 3 < ksm1 ? t + 3 : ksm1);
    computeS(1);
    loadB(t + 2 < ksm1 ? t + 2 : ksm1);
    writeA0(0);
    __syncthreads();
    loadA0(t + 4 < ksm1 ? t + 4 : ksm1);
  }
  if (ksteps & 1) computeS(0);

  #pragma unroll
  for (int mi = 0; mi < 4; ++mi) {
    const int row0 = rowBase + (mi << 4) + (fq << 2);
    #pragma unroll
    for (int ni = 0; ni < 4; ++ni) {
      const int col = (wc << 6) + (ni << 4) + fr;
      if (col < 416) {
        const float bv = (col < 400) ? bias[col] : 0.f;
        #pragma unroll
        for (int r = 0; r < 4; ++r) {
          const int row = row0 + r;
          if (row < M) C[(size_t)row * 416 + col] =
              (col < 400) ? f2bf(acc[mi][ni][r] + bv) : (unsigned short)0;
        }
      }
    }
  }
}

// ---------------- fill CSR (both layers) ----------------
__global__ void fill_csr_all(
    const int* __restrict__ src1, const int* __restrict__ dst1, const int* __restrict__ eid1,
    const int* __restrict__ indptr1, int* __restrict__ fill1, int* __restrict__ esrc1, float* __restrict__ ew1, int E1,
    const int* __restrict__ src2, const int* __restrict__ dst2, const int* __restrict__ eid2,
    const int* __restrict__ indptr2, int* __restrict__ fill2, int* __restrict__ esrc2, float* __restrict__ ew2, int E2,
    const float* __restrict__ wall)
{
  int e = blockIdx.x * 256 + threadIdx.x;
  if (e < E1) {
    int d = dst1[e];
    int pos = atomicAdd(&fill1[d], 1);
    int slot = indptr1[d] + pos;
    esrc1[slot] = src1[e];
    ew1[slot] = wall[eid1[e]];
  } else if (e < E1 + E2) {
    int e2 = e - E1;
    int d = dst2[e2];
    int pos = atomicAdd(&fill2[d], 1);
    int slot = indptr2[d] + pos;
    esrc2[slot] = src2[e2];
    ew2[slot] = wall[eid2[e2]];
  }
}

// ---------------- fused GNN layer: gather -> LDS -> GEMM (-> head + bn partials) ----------------
template<int HEAD>
__global__ __launch_bounds__(512) void fused_layer(
    const unsigned short* __restrict__ hsrc, const int* __restrict__ indptr,
    const int* __restrict__ esrc, const float* __restrict__ ew,
    const unsigned short* __restrict__ Bf, const float* __restrict__ bias,
    unsigned short* __restrict__ Cout,
    const unsigned short* __restrict__ BfH, const float* __restrict__ biasH,
    float* __restrict__ outHx, float* __restrict__ dRaw, float* __restrict__ stats, int nDst)
{
  __shared__ unsigned short T[64][456];
  const int tid = threadIdx.x;
  const int lane = tid & 63;
  const int wv = tid >> 6;
  const int rowBase = blockIdx.x * 64;
  const int fr = lane & 15;
  const int fq = lane >> 4;

  // ---- Phase 1: aggregate 8 nodes per wave into T ----
  for (int i = 0; i < 8; ++i) {
    const int row = wv * 8 + i;
    const int node = rowBase + row;
    if (lane < 52) {
      float a[8];
      if (node < nDst) {
        ushort8 v = *(const ushort8*)(hsrc + (size_t)node * 416 + lane * 8);
        #pragma unroll
        for (int j = 0; j < 8; ++j) a[j] = bf2f(v[j]);
        const int e0 = indptr[node], e1 = indptr[node + 1];
        int e = e0;
        for (; e + 8 <= e1; e += 8) {
          const int s0 = esrc[e],   s1 = esrc[e+1], s2 = esrc[e+2], s3 = esrc[e+3];
          const int s4 = esrc[e+4], s5 = esrc[e+5], s6 = esrc[e+6], s7 = esrc[e+7];
          const float w0 = ew[e],   w1 = ew[e+1], w2 = ew[e+2], w3 = ew[e+3];
          const float w4 = ew[e+4], w5 = ew[e+5], w6 = ew[e+6], w7 = ew[e+7];
          ushort8 v0 = *(const ushort8*)(hsrc + (size_t)s0 * 416 + lane * 8);
          ushort8 v1 = *(const ushort8*)(hsrc + (size_t)s1 * 416 + lane * 8);
          ushort8 v2 = *(const ushort8*)(hsrc + (size_t)s2 * 416 + lane * 8);
          ushort8 v3 = *(const ushort8*)(hsrc + (size_t)s3 * 416 + lane * 8);
          ushort8 v4 = *(const ushort8*)(hsrc + (size_t)s4 * 416 + lane * 8);
          ushort8 v5 = *(const ushort8*)(hsrc + (size_t)s5 * 416 + lane * 8);
          ushort8 v6 = *(const ushort8*)(hsrc + (size_t)s6 * 416 + lane * 8);
          ushort8 v7 = *(const ushort8*)(hsrc + (size_t)s7 * 416 + lane * 8);
          #pragma unroll
          for (int j = 0; j < 8; ++j)
            a[j] += ((bf2f(v0[j]) * w0 + bf2f(v1[j]) * w1) + (bf2f(v2[j]) * w2 + bf2f(v3[j]) * w3))
                  + ((bf2f(v4[j]) * w4 + bf2f(v5[j]) * w5) + (bf2f(v6[j]) * w6 + bf2f(v7[j]) * w7));
        }
        for (; e < e1; ++e) {
          const int s = esrc[e];
          const float w = ew[e];
          ushort8 v = *(const ushort8*)(hsrc + (size_t)s * 416 + lane * 8);
          #pragma unroll
          for (int j = 0; j < 8; ++j) a[j] += bf2f(v[j]) * w;
        }
        const float inv = 1.f / ((float)(e1 - e0) + 1.f);
        ushort8 o;
        #pragma unroll
        for (int j = 0; j < 8; ++j) o[j] = f2bf(a[j] * inv);
        *(ushort8*)&T[row][lane * 8] = o;
      } else {
        ushort8 o;
        #pragma unroll
        for (int j = 0; j < 8; ++j) o[j] = 0;
        *(ushort8*)&T[row][lane * 8] = o;
      }
    } else if (lane < 57) {
      ushort8 o;
      #pragma unroll
      for (int j = 0; j < 8; ++j) o[j] = 0;
      *(ushort8*)&T[row][416 + (lane - 52) * 8] = o;
    }
  }
  __syncthreads();

  // ---- Phase 2: 64x512 GEMM, A from LDS (no K-loop barriers), B kh-dbuf ----
  const unsigned short* bWave = Bf + ((size_t)(wv * 4) * 64 + lane) * 8;
  f32x4 acc[4][4] = {};
  bf16x8 bbA[4], bbB[4];

  auto loadBA = [&](int kh) {
    const unsigned short* bp = bWave + (size_t)kh * 16384;
    #pragma unroll
    for (int ni = 0; ni < 4; ++ni) bbA[ni] = *(const bf16x8*)(bp + ni * 512);
  };
  auto loadBB = [&](int kh) {
    const unsigned short* bp = bWave + (size_t)kh * 16384;
    #pragma unroll
    for (int ni = 0; ni < 4; ++ni) bbB[ni] = *(const bf16x8*)(bp + ni * 512);
  };
  auto computeA2 = [&](int kh) {
    bf16x8 af[4];
    #pragma unroll
    for (int mi = 0; mi < 4; ++mi)
      af[mi] = *(const bf16x8*)&T[(mi << 4) + fr][kh * 32 + (fq << 3)];
    #pragma unroll
    for (int ni = 0; ni < 4; ++ni)
      #pragma unroll
      for (int mi = 0; mi < 4; ++mi)
        acc[mi][ni] = __builtin_amdgcn_mfma_f32_16x16x32_bf16(af[mi], bbA[ni], acc[mi][ni], 0, 0, 0);
  };
  auto computeB2 = [&](int kh) {
    bf16x8 af[4];
    #pragma unroll
    for (int mi = 0; mi < 4; ++mi)
      af[mi] = *(const bf16x8*)&T[(mi << 4) + fr][kh * 32 + (fq << 3)];
    #pragma unroll
    for (int ni = 0; ni < 4; ++ni)
      #pragma unroll
      for (int mi = 0; mi < 4; ++mi)
        acc[mi][ni] = __builtin_amdgcn_mfma_f32_16x16x32_bf16(af[mi], bbB[ni], acc[mi][ni], 0, 0, 0);
  };

  loadBA(0);
  loadBB(1);
  for (int kh = 0; kh + 1 < 14; kh += 2) {
    computeA2(kh);
    loadBA(kh + 2 < 13 ? kh + 2 : 13);
    computeB2(kh + 1);
    loadBB(kh + 3 < 13 ? kh + 3 : 13);
  }

  if (HEAD == 0) {
    #pragma unroll
    for (int mi = 0; mi < 4; ++mi) {
      const int row0 = rowBase + (mi << 4) + (fq << 2);
      #pragma unroll
      for (int ni = 0; ni < 4; ++ni) {
        const int col = (wv << 6) + (ni << 4) + fr;
        if (col < 416) {
          const float bv = (col < 400) ? bias[col] : 0.f;
          #pragma unroll
          for (int r = 0; r < 4; ++r) {
            const int row = row0 + r;
            if (row < nDst) Cout[(size_t)row * 416 + col] =
                (col < 400) ? f2bf(acc[mi][ni][r] + bv) : (unsigned short)0;
          }
        }
      }
    }
  } else {
    __syncthreads();
    #pragma unroll
    for (int mi = 0; mi < 4; ++mi) {
      const int lrow0 = (mi << 4) + (fq << 2);
      #pragma unroll
      for (int ni = 0; ni < 4; ++ni) {
        const int col = (wv << 6) + (ni << 4) + fr;
        if (col < 456) {
          const float bv = (col < 400) ? bias[col] : 0.f;
          #pragma unroll
          for (int r = 0; r < 4; ++r)
            T[lrow0 + r][col] = (col < 400) ? f2bf(acc[mi][ni][r] + bv) : (unsigned short)0;
        }
      }
    }
    __syncthreads();
    // head GEMM: wave wv covers cols wv*16..wv*16+15
    const unsigned short* bhWave = BfH + ((size_t)wv * 64 + lane) * 8;
    f32x4 acc2[4] = {};
    bf16x8 bhA, bhB;
    auto loadHA = [&](int kh) { bhA = *(const bf16x8*)(bhWave + (size_t)kh * 16384); };
    auto loadHB = [&](int kh) { bhB = *(const bf16x8*)(bhWave + (size_t)kh * 16384); };
    auto computeHA = [&](int kh) {
      #pragma unroll
      for (int mi = 0; mi < 4; ++mi) {
        bf16x8 af = *(const bf16x8*)&T[(mi << 4) + fr][kh * 32 + (fq << 3)];
        acc2[mi] = __builtin_amdgcn_mfma_f32_16x16x32_bf16(af, bhA, acc2[mi], 0, 0, 0);
      }
    };
    auto computeHB = [&](int kh) {
      #pragma unroll
      for (int mi = 0; mi < 4; ++mi) {
        bf16x8 af = *(const bf16x8*)&T[(mi << 4) + fr][kh * 32 + (fq << 3)];
        acc2[mi] = __builtin_amdgcn_mfma_f32_16x16x32_bf16(af, bhB, acc2[mi], 0, 0, 0);
      }
    };
    loadHA(0);
    loadHB(1);
    for (int kh = 0; kh + 1 < 14; kh += 2) {
      computeHA(kh);
      loadHA(kh + 2 < 13 ? kh + 2 : 13);
      computeHB(kh + 1);
      loadHB(kh + 3 < 13 ? kh + 3 : 13);
    }
    const int col = (wv << 4) + fr;
    const bool colOK = (col < 70);
    const float bv = colOK ? biasH[col] : 0.f;
    if (colOK) {
      #pragma unroll
      for (int mi = 0; mi < 4; ++mi) {
        const int row0 = rowBase + (mi << 4) + (fq << 2);
        #pragma unroll
        for (int r = 0; r < 4; ++r) {
          const int row = row0 + r;
          if (row < nDst) {
            float v = acc2[mi][r] + bv;
            if (col < 20) outHx[(size_t)row * 20 + col] = v;
            else          dRaw[(size_t)row * 50 + (col - 20)] = v;
          }
        }
      }
    }
    // bn partials for cols 20..69 (fq-group reduce: partners share col)
    float s = 0.f, s2 = 0.f;
    if (col >= 20 && col < 70) {
      #pragma unroll
      for (int mi = 0; mi < 4; ++mi) {
        const int row0 = rowBase + (mi << 4) + (fq << 2);
        #pragma unroll
        for (int r = 0; r < 4; ++r) {
          if (row0 + r < nDst) {
            float v = acc2[mi][r] + bv;
            s += v; s2 += v * v;
          }
        }
      }
    }
    s  += __shfl_xor(s, 16);  s  += __shfl_xor(s, 32);
    s2 += __shfl_xor(s2, 16); s2 += __shfl_xor(s2, 32);
    if (col >= 20 && col < 70 && fq == 0) {
      atomicAdd(&stats[col - 20], s);
      atomicAdd(&stats[50 + col - 20], s2);
    }
  }
}

// ---------------- bn finalize + domain head ----------------
__global__ void domain_head2(const float* __restrict__ d, const float* __restrict__ stats,
                             const float* __restrict__ gamma, const float* __restrict__ beta,
                             const float* __restrict__ Wd2, const float* __restrict__ bd2,
                             float* __restrict__ out, int rows)
{
  __shared__ float ss[100];
  const int t = threadIdx.x;
  if (t < 50) {
    float mu = stats[t] / rows;
    float var = stats[50 + t] / rows - mu * mu;
    float inv = rsqrtf(var + 1e-5f);
    float sc = gamma[t] * inv;
    ss[t] = sc;
    ss[50 + t] = beta[t] - mu * sc;
  }
  __syncthreads();
  int r = blockIdx.x * 256 + t;
  if (r >= rows) return;
  float o0 = bd2[0], o1 = bd2[1];
  const float* dr = d + (size_t)r * 50;
  #pragma unroll 10
  for (int c = 0; c < 50; ++c) {
    float v = dr[c] * ss[c] + ss[50 + c];
    v = fmaxf(v, 0.f);
    o0 += v * Wd2[c];
    o1 += v * Wd2[50 + c];
  }
  out[r * 2]     = o0;
  out[r * 2 + 1] = o1;
}

// ---------------- launch ----------------
extern "C" void kernel_launch(void* const* d_in, const int* in_sizes, int n_in,
                              void* d_out, int out_size, void* d_ws, size_t ws_size,
                              hipStream_t stream)
{
  const float* x    = (const float*)d_in[0];
  const float* wall = (const float*)d_in[1];
  const float* Wsh  = (const float*)d_in[2];
  const float* bsh  = (const float*)d_in[3];
  const float* Whu  = (const float*)d_in[4];
  const float* bhu  = (const float*)d_in[5];
  const float* Wmo  = (const float*)d_in[6];
  const float* bmo  = (const float*)d_in[7];
  const float* Wn1  = (const float*)d_in[8];
  const float* bn1  = (const float*)d_in[9];
  const float* Wn2  = (const float*)d_in[10];
  const float* bn2  = (const float*)d_in[11];
  const float* Wlin = (const float*)d_in[12];
  const float* blin = (const float*)d_in[13];
  const float* Wd1  = (const float*)d_in[14];
  const float* bd1  = (const float*)d_in[15];
  const float* gamma= (const float*)d_in[16];
  const float* beta = (const float*)d_in[17];
  const float* Wd2  = (const float*)d_in[18];
  const float* bd2  = (const float*)d_in[19];
  const int* src1 = (const int*)d_in[20];
  const int* dst1 = (const int*)d_in[21];
  const int* eid1 = (const int*)d_in[22];
  const int* src2 = (const int*)d_in[23];
  const int* dst2 = (const int*)d_in[24];
  const int* eid2 = (const int*)d_in[25];

  char* ws = (char*)d_ws;
  unsigned short* h    = (unsigned short*)(ws);                    // [60000][416] bf16
  unsigned short* h1   = (unsigned short*)(ws + 49920000ULL);      // [30000][416]
  float* d_raw         = (float*)(ws + 74880000ULL);               // [15000][50] f32
  unsigned short* WCf  = (unsigned short*)(ws + 77880000ULL);      // 64*16384 ushorts
  unsigned short* WN1f = (unsigned short*)(ws + 79977152ULL);      // 14*16384
  unsigned short* WN2f = (unsigned short*)(ws + 80435904ULL);
  unsigned short* WHf  = (unsigned short*)(ws + 80894656ULL);
  float* b3      = (float*)(ws + 81353408ULL);
  float* bhead   = (float*)(ws + 81355456ULL);
  // contiguous zero region: cnt1,fill1,cnt2,fill2,stats
  int*   cnt1    = (int*)(ws + 81357504ULL);
  int*   fill1   = (int*)(ws + 81477504ULL);
  int*   cnt2    = (int*)(ws + 81597504ULL);
  int*   fill2   = (int*)(ws + 81657504ULL);
  float* stats   = (float*)(ws + 81717504ULL);
  int*   indptr1 = (int*)(ws + 81717904ULL);
  int*   esrc1   = (int*)(ws + 81837920ULL);
  float* ew1     = (float*)(ws + 85677920ULL);
  int*   indptr2 = (int*)(ws + 89517920ULL);
  int*   esrc2   = (int*)(ws + 89577952ULL);
  float* ew2     = (float*)(ws + 91497952ULL);

  const int E1 = 960000, E2 = 480000;
  const int N0 = 60000, N1 = 30000, N2 = 15000;

  (void)hipMemsetAsync(cnt1, 0, 360400, stream);

  // merged prep: fragments (6784 blocks) + degree count (5625) + biases (1)
  prep_all<<<6784 + 5625 + 1, 256, 0, stream>>>(
      Wsh, Whu, Wmo, Wn1, Wn2, Wlin, Wd1, WCf, WN1f, WN2f, WHf,
      bsh, bhu, bmo, blin, bd1, b3, bhead,
      dst1, cnt1, E1, dst2, cnt2, E2);

  // stage-1 GEMM (938 blocks) + embedded CSR scan (1 block)
  gemm_stage1_scan<<<939, 512, 0, stream>>>(x, WCf, b3, h, N0, 2000, 32,
                                            cnt1, indptr1, N1, cnt2, indptr2, N2);

  fill_csr_all<<<(E1 + E2 + 255) / 256, 256, 0, stream>>>(
      src1, dst1, eid1, indptr1, fill1, esrc1, ew1, E1,
      src2, dst2, eid2, indptr2, fill2, esrc2, ew2, E2, wall);

  float* out_hx  = (float*)d_out;            // 15000 x 20
  float* out_dom = (float*)d_out + 300000;   // 15000 x 2

  fused_layer<0><<<(N1 + 63) / 64, 512, 0, stream>>>(
      h, indptr1, esrc1, ew1, WN1f, bn1, h1, nullptr, nullptr, nullptr, nullptr, nullptr, N1);

  fused_layer<1><<<(N2 + 63) / 64, 512, 0, stream>>>(
      h1, indptr2, esrc2, ew2, WN2f, bn2, nullptr, WHf, bhead, out_hx, d_raw, stats, N2);

  domain_head2<<<(N2 + 255) / 256, 256, 0, stream>>>(d_raw, stats, gamma, beta, Wd2, bd2, out_dom, N2);
}

// Round 11
// 620.123 us; speedup vs baseline: 7.8347x; 1.0088x over previous
//
#include <hip/hip_runtime.h>
#include <stdint.h>
#include <stddef.h>

typedef short bf16x8 __attribute__((ext_vector_type(8)));
typedef unsigned short ushort8 __attribute__((ext_vector_type(8)));
typedef float f32x4 __attribute__((ext_vector_type(4)));

__device__ __forceinline__ unsigned short f2bf(float f) {
  union { float f; unsigned int u; } v; v.f = f;
  unsigned int r = v.u + 0x7FFFu + ((v.u >> 16) & 1u);  // RNE
  return (unsigned short)(r >> 16);
}
__device__ __forceinline__ float bf2f(unsigned short u) {
  union { unsigned int u; float f; } v; v.u = ((unsigned int)u) << 16; return v.f;
}

// ---------------- merged prep: B-fragments + degree count + biases ----------------
__global__ void prep_all(
    const float* __restrict__ Wsh, const float* __restrict__ Whu, const float* __restrict__ Wmo,
    const float* __restrict__ Wn1, const float* __restrict__ Wn2,
    const float* __restrict__ Wlin, const float* __restrict__ Wd1,
    unsigned short* __restrict__ WCf, unsigned short* __restrict__ WN1f,
    unsigned short* __restrict__ WN2f, unsigned short* __restrict__ WHf,
    const float* __restrict__ bsh, const float* __restrict__ bhu, const float* __restrict__ bmo,
    const float* __restrict__ blin, const float* __restrict__ bd1,
    float* __restrict__ b3, float* __restrict__ bhead,
    const int* __restrict__ dst1, int* __restrict__ cnt1, int E1,
    const int* __restrict__ dst2, int* __restrict__ cnt2, int E2)
{
  const int NB_FRAG = 6784;   // 106*16384/256
  const int NB_CNT  = 5625;   // (E1+E2)/256
  const int bid = blockIdx.x;
  const int tid = threadIdx.x;
  if (bid < NB_FRAG) {
    const int s0 = 64 * 16384, s1 = s0 + 14 * 16384, s2 = s1 + 14 * 16384;
    int idx = bid * 256 + tid;
    int mode, rel;
    unsigned short* out;
    if (idx < s0)      { mode = 0; rel = idx;      out = WCf;  }
    else if (idx < s1) { mode = 1; rel = idx - s0; out = WN1f; }
    else if (idx < s2) { mode = 3; rel = idx - s1; out = WN2f; }
    else               { mode = 2; rel = idx - s2; out = WHf;  }
    int t = rel >> 14;
    int rem = rel & 16383;
    int e = rem & 7;
    int chunk = rem >> 3;
    int lane = chunk & 63;
    int g = chunk >> 6;
    int col = g * 16 + (lane & 15);
    int k = t * 32 + ((lane >> 4) << 3) + e;
    float v = 0.f;
    if (mode == 0) {
      if (col < 400 && k < 2000) {
        if (k < 1000)      v = Wsh[col * 1000 + k];
        else if (k < 1500) v = Whu[col * 500 + (k - 1000)];
        else               v = Wmo[col * 500 + (k - 1500)];
      }
    } else if (mode == 1) {
      if (col < 400 && k < 400) v = Wn1[col * 400 + k];
    } else if (mode == 3) {
      if (col < 400 && k < 400) v = Wn2[col * 400 + k];
    } else {
      if (k < 400) {
        if (col < 20)      v = Wlin[col * 400 + k];
        else if (col < 70) v = Wd1[(col - 20) * 400 + k];
      }
    }
    out[rel] = f2bf(v);
  } else if (bid < NB_FRAG + NB_CNT) {
    int e = (bid - NB_FRAG) * 256 + tid;
    if (e < E1) atomicAdd(&cnt1[dst1[e]], 1);
    else if (e < E1 + E2) atomicAdd(&cnt2[dst2[e - E1]], 1);
  } else {
    for (int t = tid; t < 512; t += 256) {
      if (t < 416) b3[t] = (t < 400) ? (bsh[t] + bhu[t] + bmo[t]) : 0.f;
      bhead[t] = (t < 20) ? blin[t] : ((t < 70) ? bd1[t - 20] : 0.f);
    }
  }
}

// ---------------- 256-thread exclusive scan helper ----------------
__device__ void scan256(const int* __restrict__ cnt, int* __restrict__ indptr, int n,
                        int* sh, int* carrySh)
{
  const int t = threadIdx.x;
  if (t == 0) *carrySh = 0;
  __syncthreads();
  for (int base = 0; base < n; base += 4096) {
    int v[16]; int tsum = 0;
    #pragma unroll
    for (int i = 0; i < 16; ++i) {
      int idx = base + t * 16 + i;
      v[i] = (idx < n) ? cnt[idx] : 0;
      tsum += v[i];
    }
    sh[t] = tsum; __syncthreads();
    for (int off = 1; off < 256; off <<= 1) {
      int add = (t >= off) ? sh[t - off] : 0;
      __syncthreads();
      sh[t] += add;
      __syncthreads();
    }
    int excl = *carrySh + sh[t] - tsum;
    #pragma unroll
    for (int i = 0; i < 16; ++i) {
      int idx = base + t * 16 + i;
      if (idx < n) indptr[idx] = excl;
      excl += v[i];
    }
    __syncthreads();
    if (t == 255) *carrySh += sh[255];
    __syncthreads();
  }
  if (t == 0) indptr[n] = *carrySh;
  __syncthreads();
}

// ---------------- stage-1 GEMM: 64x512 block, 256 thr = 4 waves, wave 64x128 (ni=8) ----------------
// BK=32, ksteps=63 (odd). A: LDS dbuf pad-36, 2-step named-set reg prefetch.
// B: bb[8] single-buffer from fragment-order global (L2). Last block: CSR scans.
__global__ __launch_bounds__(256, 2) void gemm_stage1_scan(
    const float* __restrict__ Af, const unsigned short* __restrict__ Bf,
    const float* __restrict__ bias, unsigned short* __restrict__ C,
    int M, int Kreal, int ksteps,
    const int* __restrict__ cnt1, int* __restrict__ indptr1, int n1,
    const int* __restrict__ cnt2, int* __restrict__ indptr2, int n2)
{
  __shared__ unsigned short As[2][64][36];
  __shared__ int sh[256];
  __shared__ int carrySh;

  if (blockIdx.x == gridDim.x - 1) {
    scan256(cnt1, indptr1, n1, sh, &carrySh);
    scan256(cnt2, indptr2, n2, sh, &carrySh);
    return;
  }

  const int tid = threadIdx.x;
  const int lane = tid & 63;
  const int wc = tid >> 6;            // 0..3
  const int rowBase = blockIdx.x * 64;
  const int sRow = tid >> 2;          // 0..63
  const int sC = (tid & 3) << 3;      // 0,8,16,24
  const int aRow = rowBase + sRow;
  const bool aOK = aRow < M;
  const int fr = lane & 15;
  const int fq = lane >> 4;

  const unsigned short* bWave = Bf + ((size_t)(wc * 8) * 64 + lane) * 8;

  f32x4 acc[4][8] = {};
  f32x4 a0lo, a0hi, a1lo, a1hi;   // named A staging sets
  bf16x8 bb[8];

  auto loadB = [&](int t) {
    const unsigned short* bp = bWave + (size_t)t * 16384;
    #pragma unroll
    for (int ni = 0; ni < 8; ++ni) bb[ni] = *(const bf16x8*)(bp + ni * 512);
  };
  auto loadA0 = [&](int t) {
    const int k0 = t * 32 + sC;
    if (aOK && (k0 + 4) <= Kreal) a0lo = *(const f32x4*)(Af + (size_t)aRow * Kreal + k0);
    else { a0lo[0]=0.f; a0lo[1]=0.f; a0lo[2]=0.f; a0lo[3]=0.f; }
    if (aOK && (k0 + 8) <= Kreal) a0hi = *(const f32x4*)(Af + (size_t)aRow * Kreal + k0 + 4);
    else { a0hi[0]=0.f; a0hi[1]=0.f; a0hi[2]=0.f; a0hi[3]=0.f; }
  };
  auto loadA1 = [&](int t) {
    const int k0 = t * 32 + sC;
    if (aOK && (k0 + 4) <= Kreal) a1lo = *(const f32x4*)(Af + (size_t)aRow * Kreal + k0);
    else { a1lo[0]=0.f; a1lo[1]=0.f; a1lo[2]=0.f; a1lo[3]=0.f; }
    if (aOK && (k0 + 8) <= Kreal) a1hi = *(const f32x4*)(Af + (size_t)aRow * Kreal + k0 + 4);
    else { a1hi[0]=0.f; a1hi[1]=0.f; a1hi[2]=0.f; a1hi[3]=0.f; }
  };
  auto writeA0 = [&](int buf) {
    ushort8 w;
    w[0]=f2bf(a0lo[0]); w[1]=f2bf(a0lo[1]); w[2]=f2bf(a0lo[2]); w[3]=f2bf(a0lo[3]);
    w[4]=f2bf(a0hi[0]); w[5]=f2bf(a0hi[1]); w[6]=f2bf(a0hi[2]); w[7]=f2bf(a0hi[3]);
    *(ushort8*)&As[buf][sRow][sC] = w;
  };
  auto writeA1 = [&](int buf) {
    ushort8 w;
    w[0]=f2bf(a1lo[0]); w[1]=f2bf(a1lo[1]); w[2]=f2bf(a1lo[2]); w[3]=f2bf(a1lo[3]);
    w[4]=f2bf(a1hi[0]); w[5]=f2bf(a1hi[1]); w[6]=f2bf(a1hi[2]); w[7]=f2bf(a1hi[3]);
    *(ushort8*)&As[buf][sRow][sC] = w;
  };
  auto compute = [&](int buf) {
    bf16x8 af[4];
    #pragma unroll
    for (int mi = 0; mi < 4; ++mi)
      af[mi] = *(const bf16x8*)&As[buf][(mi << 4) + fr][fq << 3];
    #pragma unroll
    for (int ni = 0; ni < 8; ++ni)
      #pragma unroll
      for (int mi = 0; mi < 4; ++mi)
        acc[mi][ni] = __builtin_amdgcn_mfma_f32_16x16x32_bf16(af[mi], bb[ni], acc[mi][ni], 0, 0, 0);
  };

  const int ksm1 = ksteps - 1;
  loadA0(0);
  loadB(0);
  loadA1(1 < ksm1 ? 1 : ksm1);
  writeA0(0);
  __syncthreads();
  loadA0(2 < ksm1 ? 2 : ksm1);

  for (int t = 0; t + 1 < ksteps; t += 2) {
    compute(0);
    loadB(t + 1);
    writeA1(1);
    __syncthreads();
    loadA1(t + 3 < ksm1 ? t + 3 : ksm1);
    compute(1);
    loadB(t + 2 < ksm1 ? t + 2 : ksm1);
    writeA0(0);
    __syncthreads();
    loadA0(t + 4 < ksm1 ? t + 4 : ksm1);
  }
  compute(0);   // tail (ksteps odd)

  #pragma unroll
  for (int mi = 0; mi < 4; ++mi) {
    const int row0 = rowBase + (mi << 4) + (fq << 2);
    #pragma unroll
    for (int ni = 0; ni < 8; ++ni) {
      const int col = (wc << 7) + (ni << 4) + fr;
      if (col < 416) {
        const float bv = (col < 400) ? bias[col] : 0.f;
        #pragma unroll
        for (int r = 0; r < 4; ++r) {
          const int row = row0 + r;
          if (row < M) C[(size_t)row * 416 + col] =
              (col < 400) ? f2bf(acc[mi][ni][r] + bv) : (unsigned short)0;
        }
      }
    }
  }
}

// ---------------- fill CSR (both layers) ----------------
__global__ void fill_csr_all(
    const int* __restrict__ src1, const int* __restrict__ dst1, const int* __restrict__ eid1,
    const int* __restrict__ indptr1, int* __restrict__ fill1, int* __restrict__ esrc1, float* __restrict__ ew1, int E1,
    const int* __restrict__ src2, const int* __restrict__ dst2, const int* __restrict__ eid2,
    const int* __restrict__ indptr2, int* __restrict__ fill2, int* __restrict__ esrc2, float* __restrict__ ew2, int E2,
    const float* __restrict__ wall)
{
  int e = blockIdx.x * 256 + threadIdx.x;
  if (e < E1) {
    int d = dst1[e];
    int pos = atomicAdd(&fill1[d], 1);
    int slot = indptr1[d] + pos;
    esrc1[slot] = src1[e];
    ew1[slot] = wall[eid1[e]];
  } else if (e < E1 + E2) {
    int e2 = e - E1;
    int d = dst2[e2];
    int pos = atomicAdd(&fill2[d], 1);
    int slot = indptr2[d] + pos;
    esrc2[slot] = src2[e2];
    ew2[slot] = wall[eid2[e2]];
  }
}

// ---------------- fused GNN layer: gather -> LDS -> GEMM (-> head + bn partials) ----------------
// ROWS = dst nodes per block (64 or 32). 512 thr = 8 waves.
template<int HEAD, int ROWS>
__global__ __launch_bounds__(512) void fused_layer(
    const unsigned short* __restrict__ hsrc, const int* __restrict__ indptr,
    const int* __restrict__ esrc, const float* __restrict__ ew,
    const unsigned short* __restrict__ Bf, const float* __restrict__ bias,
    unsigned short* __restrict__ Cout,
    const unsigned short* __restrict__ BfH, const float* __restrict__ biasH,
    float* __restrict__ outHx, float* __restrict__ dRaw, float* __restrict__ stats, int nDst)
{
  constexpr int MI = ROWS / 16;
  constexpr int NPW = ROWS / 8;        // nodes per wave
  __shared__ unsigned short T[ROWS][456];
  const int tid = threadIdx.x;
  const int lane = tid & 63;
  const int wv = tid >> 6;
  const int rowBase = blockIdx.x * ROWS;
  const int fr = lane & 15;
  const int fq = lane >> 4;

  // ---- Phase 1: aggregate NPW nodes per wave into T (16-deep edge unroll) ----
  for (int i = 0; i < NPW; ++i) {
    const int row = wv * NPW + i;
    const int node = rowBase + row;
    if (lane < 52) {
      float a[8];
      if (node < nDst) {
        ushort8 v = *(const ushort8*)(hsrc + (size_t)node * 416 + lane * 8);
        #pragma unroll
        for (int j = 0; j < 8; ++j) a[j] = bf2f(v[j]);
        const int e0 = indptr[node], e1 = indptr[node + 1];
        int e = e0;
        for (; e + 16 <= e1; e += 16) {
          int ss[16]; float ww[16];
          #pragma unroll
          for (int u = 0; u < 16; ++u) { ss[u] = esrc[e + u]; ww[u] = ew[e + u]; }
          ushort8 q0  = *(const ushort8*)(hsrc + (size_t)ss[0]  * 416 + lane * 8);
          ushort8 q1  = *(const ushort8*)(hsrc + (size_t)ss[1]  * 416 + lane * 8);
          ushort8 q2  = *(const ushort8*)(hsrc + (size_t)ss[2]  * 416 + lane * 8);
          ushort8 q3  = *(const ushort8*)(hsrc + (size_t)ss[3]  * 416 + lane * 8);
          ushort8 q4  = *(const ushort8*)(hsrc + (size_t)ss[4]  * 416 + lane * 8);
          ushort8 q5  = *(const ushort8*)(hsrc + (size_t)ss[5]  * 416 + lane * 8);
          ushort8 q6  = *(const ushort8*)(hsrc + (size_t)ss[6]  * 416 + lane * 8);
          ushort8 q7  = *(const ushort8*)(hsrc + (size_t)ss[7]  * 416 + lane * 8);
          ushort8 q8  = *(const ushort8*)(hsrc + (size_t)ss[8]  * 416 + lane * 8);
          ushort8 q9  = *(const ushort8*)(hsrc + (size_t)ss[9]  * 416 + lane * 8);
          ushort8 q10 = *(const ushort8*)(hsrc + (size_t)ss[10] * 416 + lane * 8);
          ushort8 q11 = *(const ushort8*)(hsrc + (size_t)ss[11] * 416 + lane * 8);
          ushort8 q12 = *(const ushort8*)(hsrc + (size_t)ss[12] * 416 + lane * 8);
          ushort8 q13 = *(const ushort8*)(hsrc + (size_t)ss[13] * 416 + lane * 8);
          ushort8 q14 = *(const ushort8*)(hsrc + (size_t)ss[14] * 416 + lane * 8);
          ushort8 q15 = *(const ushort8*)(hsrc + (size_t)ss[15] * 416 + lane * 8);
          #pragma unroll
          for (int j = 0; j < 8; ++j) {
            float p0 = (bf2f(q0[j])*ww[0] + bf2f(q1[j])*ww[1]) + (bf2f(q2[j])*ww[2] + bf2f(q3[j])*ww[3]);
            float p1 = (bf2f(q4[j])*ww[4] + bf2f(q5[j])*ww[5]) + (bf2f(q6[j])*ww[6] + bf2f(q7[j])*ww[7]);
            float p2 = (bf2f(q8[j])*ww[8] + bf2f(q9[j])*ww[9]) + (bf2f(q10[j])*ww[10] + bf2f(q11[j])*ww[11]);
            float p3 = (bf2f(q12[j])*ww[12] + bf2f(q13[j])*ww[13]) + (bf2f(q14[j])*ww[14] + bf2f(q15[j])*ww[15]);
            a[j] += (p0 + p1) + (p2 + p3);
          }
        }
        for (; e + 4 <= e1; e += 4) {
          const int s0 = esrc[e], s1 = esrc[e+1], s2 = esrc[e+2], s3 = esrc[e+3];
          const float w0 = ew[e], w1 = ew[e+1], w2 = ew[e+2], w3 = ew[e+3];
          ushort8 q0 = *(const ushort8*)(hsrc + (size_t)s0 * 416 + lane * 8);
          ushort8 q1 = *(const ushort8*)(hsrc + (size_t)s1 * 416 + lane * 8);
          ushort8 q2 = *(const ushort8*)(hsrc + (size_t)s2 * 416 + lane * 8);
          ushort8 q3 = *(const ushort8*)(hsrc + (size_t)s3 * 416 + lane * 8);
          #pragma unroll
          for (int j = 0; j < 8; ++j)
            a[j] += (bf2f(q0[j]) * w0 + bf2f(q1[j]) * w1) + (bf2f(q2[j]) * w2 + bf2f(q3[j]) * w3);
        }
        for (; e < e1; ++e) {
          const int s = esrc[e];
          const float w = ew[e];
          ushort8 q = *(const ushort8*)(hsrc + (size_t)s * 416 + lane * 8);
          #pragma unroll
          for (int j = 0; j < 8; ++j) a[j] += bf2f(q[j]) * w;
        }
        const float inv = 1.f / ((float)(e1 - e0) + 1.f);
        ushort8 o;
        #pragma unroll
        for (int j = 0; j < 8; ++j) o[j] = f2bf(a[j] * inv);
        *(ushort8*)&T[row][lane * 8] = o;
      } else {
        ushort8 o;
        #pragma unroll
        for (int j = 0; j < 8; ++j) o[j] = 0;
        *(ushort8*)&T[row][lane * 8] = o;
      }
    } else if (lane < 57) {
      ushort8 o;
      #pragma unroll
      for (int j = 0; j < 8; ++j) o[j] = 0;
      *(ushort8*)&T[row][416 + (lane - 52) * 8] = o;
    }
  }
  __syncthreads();

  // ---- Phase 2: ROWSx512 GEMM, A from LDS (no K-loop barriers), B kh-dbuf ----
  const unsigned short* bWave = Bf + ((size_t)(wv * 4) * 64 + lane) * 8;
  f32x4 acc[MI][4] = {};
  bf16x8 bbA[4], bbB[4];

  auto loadBA = [&](int kh) {
    const unsigned short* bp = bWave + (size_t)kh * 16384;
    #pragma unroll
    for (int ni = 0; ni < 4; ++ni) bbA[ni] = *(const bf16x8*)(bp + ni * 512);
  };
  auto loadBB = [&](int kh) {
    const unsigned short* bp = bWave + (size_t)kh * 16384;
    #pragma unroll
    for (int ni = 0; ni < 4; ++ni) bbB[ni] = *(const bf16x8*)(bp + ni * 512);
  };
  auto computeA2 = [&](int kh) {
    bf16x8 af[MI];
    #pragma unroll
    for (int mi = 0; mi < MI; ++mi)
      af[mi] = *(const bf16x8*)&T[(mi << 4) + fr][kh * 32 + (fq << 3)];
    #pragma unroll
    for (int ni = 0; ni < 4; ++ni)
      #pragma unroll
      for (int mi = 0; mi < MI; ++mi)
        acc[mi][ni] = __builtin_amdgcn_mfma_f32_16x16x32_bf16(af[mi], bbA[ni], acc[mi][ni], 0, 0, 0);
  };
  auto computeB2 = [&](int kh) {
    bf16x8 af[MI];
    #pragma unroll
    for (int mi = 0; mi < MI; ++mi)
      af[mi] = *(const bf16x8*)&T[(mi << 4) + fr][kh * 32 + (fq << 3)];
    #pragma unroll
    for (int ni = 0; ni < 4; ++ni)
      #pragma unroll
      for (int mi = 0; mi < MI; ++mi)
        acc[mi][ni] = __builtin_amdgcn_mfma_f32_16x16x32_bf16(af[mi], bbB[ni], acc[mi][ni], 0, 0, 0);
  };

  loadBA(0);
  loadBB(1);
  for (int kh = 0; kh + 1 < 14; kh += 2) {
    computeA2(kh);
    loadBA(kh + 2 < 13 ? kh + 2 : 13);
    computeB2(kh + 1);
    loadBB(kh + 3 < 13 ? kh + 3 : 13);
  }

  if (HEAD == 0) {
    #pragma unroll
    for (int mi = 0; mi < MI; ++mi) {
      const int row0 = rowBase + (mi << 4) + (fq << 2);
      #pragma unroll
      for (int ni = 0; ni < 4; ++ni) {
        const int col = (wv << 6) + (ni << 4) + fr;
        if (col < 416) {
          const float bv = (col < 400) ? bias[col] : 0.f;
          #pragma unroll
          for (int r = 0; r < 4; ++r) {
            const int row = row0 + r;
            if (row < nDst) Cout[(size_t)row * 416 + col] =
                (col < 400) ? f2bf(acc[mi][ni][r] + bv) : (unsigned short)0;
          }
        }
      }
    }
  } else {
    __syncthreads();
    #pragma unroll
    for (int mi = 0; mi < MI; ++mi) {
      const int lrow0 = (mi << 4) + (fq << 2);
      #pragma unroll
      for (int ni = 0; ni < 4; ++ni) {
        const int col = (wv << 6) + (ni << 4) + fr;
        if (col < 456) {
          const float bv = (col < 400) ? bias[col] : 0.f;
          #pragma unroll
          for (int r = 0; r < 4; ++r)
            T[lrow0 + r][col] = (col < 400) ? f2bf(acc[mi][ni][r] + bv) : (unsigned short)0;
        }
      }
    }
    __syncthreads();
    const unsigned short* bhWave = BfH + ((size_t)wv * 64 + lane) * 8;
    f32x4 acc2[MI] = {};
    bf16x8 bhA, bhB;
    auto loadHA = [&](int kh) { bhA = *(const bf16x8*)(bhWave + (size_t)kh * 16384); };
    auto loadHB = [&](int kh) { bhB = *(const bf16x8*)(bhWave + (size_t)kh * 16384); };
    auto computeHA = [&](int kh) {
      #pragma unroll
      for (int mi = 0; mi < MI; ++mi) {
        bf16x8 af = *(const bf16x8*)&T[(mi << 4) + fr][kh * 32 + (fq << 3)];
        acc2[mi] = __builtin_amdgcn_mfma_f32_16x16x32_bf16(af, bhA, acc2[mi], 0, 0, 0);
      }
    };
    auto computeHB = [&](int kh) {
      #pragma unroll
      for (int mi = 0; mi < MI; ++mi) {
        bf16x8 af = *(const bf16x8*)&T[(mi << 4) + fr][kh * 32 + (fq << 3)];
        acc2[mi] = __builtin_amdgcn_mfma_f32_16x16x32_bf16(af, bhB, acc2[mi], 0, 0, 0);
      }
    };
    loadHA(0);
    loadHB(1);
    for (int kh = 0; kh + 1 < 14; kh += 2) {
      computeHA(kh);
      loadHA(kh + 2 < 13 ? kh + 2 : 13);
      computeHB(kh + 1);
      loadHB(kh + 3 < 13 ? kh + 3 : 13);
    }
    const int col = (wv << 4) + fr;
    const bool colOK = (col < 70);
    const float bv = colOK ? biasH[col] : 0.f;
    if (colOK) {
      #pragma unroll
      for (int mi = 0; mi < MI; ++mi) {
        const int row0 = rowBase + (mi << 4) + (fq << 2);
        #pragma unroll
        for (int r = 0; r < 4; ++r) {
          const int row = row0 + r;
          if (row < nDst) {
            float v = acc2[mi][r] + bv;
            if (col < 20) outHx[(size_t)row * 20 + col] = v;
            else          dRaw[(size_t)row * 50 + (col - 20)] = v;
          }
        }
      }
    }
    float s = 0.f, s2 = 0.f;
    if (col >= 20 && col < 70) {
      #pragma unroll
      for (int mi = 0; mi < MI; ++mi) {
        const int row0 = rowBase + (mi << 4) + (fq << 2);
        #pragma unroll
        for (int r = 0; r < 4; ++r) {
          if (row0 + r < nDst) {
            float v = acc2[mi][r] + bv;
            s += v; s2 += v * v;
          }
        }
      }
    }
    s  += __shfl_xor(s, 16);  s  += __shfl_xor(s, 32);
    s2 += __shfl_xor(s2, 16); s2 += __shfl_xor(s2, 32);
    if (col >= 20 && col < 70 && fq == 0) {
      atomicAdd(&stats[col - 20], s);
      atomicAdd(&stats[50 + col - 20], s2);
    }
  }
}

// ---------------- bn finalize + domain head ----------------
__global__ void domain_head2(const float* __restrict__ d, const float* __restrict__ stats,
                             const float* __restrict__ gamma, const float* __restrict__ beta,
                             const float* __restrict__ Wd2, const float* __restrict__ bd2,
                             float* __restrict__ out, int rows)
{
  __shared__ float ss[100];
  const int t = threadIdx.x;
  if (t < 50) {
    float mu = stats[t] / rows;
    float var = stats[50 + t] / rows - mu * mu;
    float inv = rsqrtf(var + 1e-5f);
    float sc = gamma[t] * inv;
    ss[t] = sc;
    ss[50 + t] = beta[t] - mu * sc;
  }
  __syncthreads();
  int r = blockIdx.x * 256 + t;
  if (r >= rows) return;
  float o0 = bd2[0], o1 = bd2[1];
  const float* dr = d + (size_t)r * 50;
  #pragma unroll 10
  for (int c = 0; c < 50; ++c) {
    float v = dr[c] * ss[c] + ss[50 + c];
    v = fmaxf(v, 0.f);
    o0 += v * Wd2[c];
    o1 += v * Wd2[50 + c];
  }
  out[r * 2]     = o0;
  out[r * 2 + 1] = o1;
}

// ---------------- launch ----------------
extern "C" void kernel_launch(void* const* d_in, const int* in_sizes, int n_in,
                              void* d_out, int out_size, void* d_ws, size_t ws_size,
                              hipStream_t stream)
{
  const float* x    = (const float*)d_in[0];
  const float* wall = (const float*)d_in[1];
  const float* Wsh  = (const float*)d_in[2];
  const float* bsh  = (const float*)d_in[3];
  const float* Whu  = (const float*)d_in[4];
  const float* bhu  = (const float*)d_in[5];
  const float* Wmo  = (const float*)d_in[6];
  const float* bmo  = (const float*)d_in[7];
  const float* Wn1  = (const float*)d_in[8];
  const float* bn1  = (const float*)d_in[9];
  const float* Wn2  = (const float*)d_in[10];
  const float* bn2  = (const float*)d_in[11];
  const float* Wlin = (const float*)d_in[12];
  const float* blin = (const float*)d_in[13];
  const float* Wd1  = (const float*)d_in[14];
  const float* bd1  = (const float*)d_in[15];
  const float* gamma= (const float*)d_in[16];
  const float* beta = (const float*)d_in[17];
  const float* Wd2  = (const float*)d_in[18];
  const float* bd2  = (const float*)d_in[19];
  const int* src1 = (const int*)d_in[20];
  const int* dst1 = (const int*)d_in[21];
  const int* eid1 = (const int*)d_in[22];
  const int* src2 = (const int*)d_in[23];
  const int* dst2 = (const int*)d_in[24];
  const int* eid2 = (const int*)d_in[25];

  char* ws = (char*)d_ws;
  unsigned short* h    = (unsigned short*)(ws);                    // [60000][416] bf16
  unsigned short* h1   = (unsigned short*)(ws + 49920000ULL);      // [30000][416]
  float* d_raw         = (float*)(ws + 74880000ULL);               // [15000][50] f32
  unsigned short* WCf  = (unsigned short*)(ws + 77880000ULL);      // 64*16384 ushorts
  unsigned short* WN1f = (unsigned short*)(ws + 79977152ULL);      // 14*16384
  unsigned short* WN2f = (unsigned short*)(ws + 80435904ULL);
  unsigned short* WHf  = (unsigned short*)(ws + 80894656ULL);
  float* b3      = (float*)(ws + 81353408ULL);
  float* bhead   = (float*)(ws + 81355456ULL);
  int*   cnt1    = (int*)(ws + 81357504ULL);
  int*   fill1   = (int*)(ws + 81477504ULL);
  int*   cnt2    = (int*)(ws + 81597504ULL);
  int*   fill2   = (int*)(ws + 81657504ULL);
  float* stats   = (float*)(ws + 81717504ULL);
  int*   indptr1 = (int*)(ws + 81717904ULL);
  int*   esrc1   = (int*)(ws + 81837920ULL);
  float* ew1     = (float*)(ws + 85677920ULL);
  int*   indptr2 = (int*)(ws + 89517920ULL);
  int*   esrc2   = (int*)(ws + 89577952ULL);
  float* ew2     = (float*)(ws + 91497952ULL);

  const int E1 = 960000, E2 = 480000;
  const int N0 = 60000, N1 = 30000, N2 = 15000;

  (void)hipMemsetAsync(cnt1, 0, 360400, stream);

  prep_all<<<6784 + 5625 + 1, 256, 0, stream>>>(
      Wsh, Whu, Wmo, Wn1, Wn2, Wlin, Wd1, WCf, WN1f, WN2f, WHf,
      bsh, bhu, bmo, blin, bd1, b3, bhead,
      dst1, cnt1, E1, dst2, cnt2, E2);

  // stage-1 GEMM (938 blocks, 256 thr, ni=8, BK=32, ksteps=63) + embedded scan (1 block)
  gemm_stage1_scan<<<939, 256, 0, stream>>>(x, WCf, b3, h, N0, 2000, 63,
                                            cnt1, indptr1, N1, cnt2, indptr2, N2);

  fill_csr_all<<<(E1 + E2 + 255) / 256, 256, 0, stream>>>(
      src1, dst1, eid1, indptr1, fill1, esrc1, ew1, E1,
      src2, dst2, eid2, indptr2, fill2, esrc2, ew2, E2, wall);

  float* out_hx  = (float*)d_out;            // 15000 x 20
  float* out_dom = (float*)d_out + 300000;   // 15000 x 2

  fused_layer<0, 64><<<(N1 + 63) / 64, 512, 0, stream>>>(
      h, indptr1, esrc1, ew1, WN1f, bn1, h1, nullptr, nullptr, nullptr, nullptr, nullptr, N1);

  fused_layer<1, 32><<<(N2 + 31) / 32, 512, 0, stream>>>(
      h1, indptr2, esrc2, ew2, WN2f, bn2, nullptr, WHf, bhead, out_hx, d_raw, stats, N2);

  domain_head2<<<(N2 + 255) / 256, 256, 0, stream>>>(d_raw, stats, gamma, beta, Wd2, bd2, out_dom, N2);
}